// Round 4
// baseline (5190.755 us; speedup 1.0000x reference)
//
#include <hip/hip_runtime.h>
#include <math.h>

typedef unsigned short ushort_t;
typedef unsigned int uint32;

#define B_ 2
#define T_ 4096
#define DIM_ 512
#define H_ 8
#define DH_ 64
#define BH_ 16
#define NHASH_ 8
#define NB_ 64
#define NCH_ 512
#define FF_ 2048
#define TAGS_ 17
#define ROWS_ 8192
#define SORTN_ 32768

__device__ __forceinline__ float bf2f(ushort_t u){
  return __uint_as_float(((uint32)u) << 16);
}
__device__ __forceinline__ ushort_t f2bf(float f){
  uint32 u = __float_as_uint(f);
  u += 0x7fffu + ((u >> 16) & 1u);
  return (ushort_t)(u >> 16);
}

// ---------------- embed: x = tok_emb[X] + axial pos, duplicated into x1,x2
__global__ __launch_bounds__(256) void k_embed(const int* __restrict__ X,
                                               const float* __restrict__ tok,
                                               const float* __restrict__ ax1,
                                               const float* __restrict__ ax2,
                                               float* __restrict__ x1, float* __restrict__ x2){
  int row = blockIdx.x;               // b*T + t
  int t = row & (T_-1);
  int tokid = X[row];
  size_t base = (size_t)row * DIM_;
  for (int d = threadIdx.x; d < DIM_; d += 256){
    float e = tok[(size_t)tokid*DIM_ + d];
    float p = (d < 256) ? ax1[(t>>6)*256 + d] : ax2[(t&63)*256 + (d-256)];
    float v = e + p;
    x1[base+d] = v; x2[base+d] = v;
  }
}

// ---------------- layernorm (optionally averaging two inputs first)
__global__ __launch_bounds__(256) void k_ln(const float* __restrict__ A, const float* __restrict__ Bb,
                                            const float* __restrict__ g, const float* __restrict__ be,
                                            float* __restrict__ Y){
  int row = blockIdx.x; int tid = threadIdx.x;
  size_t base = (size_t)row * DIM_;
  float x0 = A[base+tid], x1v = A[base+tid+256];
  if (Bb){ x0 = 0.5f*(x0 + Bb[base+tid]); x1v = 0.5f*(x1v + Bb[base+tid+256]); }
  float s = x0 + x1v, sq = x0*x0 + x1v*x1v;
  for (int o=32;o>0;o>>=1){ s += __shfl_down(s,o); sq += __shfl_down(sq,o); }
  __shared__ float ls[4], lq[4], mm[2];
  if ((tid&63)==0){ ls[tid>>6]=s; lq[tid>>6]=sq; }
  __syncthreads();
  if (tid==0){
    float S=ls[0]+ls[1]+ls[2]+ls[3], Q=lq[0]+lq[1]+lq[2]+lq[3];
    float m = S*(1.0f/DIM_); float var = Q*(1.0f/DIM_) - m*m;
    mm[0]=m; mm[1]=1.0f/sqrtf(var+1e-5f);
  }
  __syncthreads();
  float m=mm[0], r=mm[1];
  Y[base+tid]     = (x0 -m)*r*g[tid]     + be[tid];
  Y[base+tid+256] = (x1v-m)*r*g[tid+256] + be[tid+256];
}

// ---------------- generic tiled GEMM: C(MxN) op= act(A(MxK) @ W(KxN) + bias)
// flags: 1 = accumulate into C (residual), 2 = gelu(tanh)
__global__ __launch_bounds__(256) void k_gemm(const float* __restrict__ A,
                                              const float* __restrict__ W,
                                              const float* __restrict__ bias,
                                              float* __restrict__ C,
                                              int M, int N, int K, int flags){
  __shared__ float As[32][68];
  __shared__ float Bs[32][64];
  int bn = blockIdx.x * 64, bm = blockIdx.y * 64;
  int tid = threadIdx.x;
  int tx = tid & 15, ty = tid >> 4;
  float acc[4][4];
  #pragma unroll
  for (int r=0;r<4;r++){
    #pragma unroll
    for (int cc=0;cc<4;cc++) acc[r][cc]=0.f;
  }
  for (int k0=0; k0<K; k0+=32){
    for (int idx = tid; idx < 64*32; idx += 256){
      int mm = idx >> 5, kk = idx & 31;
      As[kk][mm] = A[(size_t)(bm+mm)*K + k0 + kk];
    }
    for (int idx = tid; idx < 32*64; idx += 256){
      int kk = idx >> 6, nn = idx & 63;
      Bs[kk][nn] = W[(size_t)(k0+kk)*N + bn + nn];
    }
    __syncthreads();
    #pragma unroll
    for (int kk=0; kk<32; kk++){
      float4 a  = *(const float4*)&As[kk][ty*4];
      float4 bv = *(const float4*)&Bs[kk][tx*4];
      acc[0][0] += a.x*bv.x; acc[0][1] += a.x*bv.y; acc[0][2] += a.x*bv.z; acc[0][3] += a.x*bv.w;
      acc[1][0] += a.y*bv.x; acc[1][1] += a.y*bv.y; acc[1][2] += a.y*bv.z; acc[1][3] += a.y*bv.w;
      acc[2][0] += a.z*bv.x; acc[2][1] += a.z*bv.y; acc[2][2] += a.z*bv.z; acc[2][3] += a.z*bv.w;
      acc[3][0] += a.w*bv.x; acc[3][1] += a.w*bv.y; acc[3][2] += a.w*bv.z; acc[3][3] += a.w*bv.w;
    }
    __syncthreads();
  }
  #pragma unroll
  for (int r=0;r<4;r++){
    int mm = bm + ty*4 + r;
    #pragma unroll
    for (int cc=0;cc<4;cc++){
      int nn = bn + tx*4 + cc;
      float v = acc[r][cc];
      if (bias) v += bias[nn];
      if (flags & 2){
        float x = v;
        float inner = 0.7978845608028654f * (x + 0.044715f*x*x*x);
        v = 0.5f*x*(1.0f + tanhf(inner));
      }
      size_t off = (size_t)mm*N + nn;
      if (flags & 1) C[off] += v;
      else C[off] = v;
    }
  }
}

// ---------------- LSH bucketing: argmax over [rot.qk, -rot.qk]
// grid: (T/64, NHASH, BH); block 256 = 64 tokens x 4 lanes; one hash per block.
__global__ __launch_bounds__(256) void k_buckets(const float* __restrict__ qk,
                                                 const float* __restrict__ rot,
                                                 int* __restrict__ buckets){
  __shared__ float rotS[DH_][32];      // 8 KB, fp32 rot slice for this hash
  __shared__ float qs[64][68];         // 17.4 KB
  int t0 = blockIdx.x * 64;
  int h  = blockIdx.y;
  int bh = blockIdx.z;
  int b = bh >> 3, head = bh & 7;
  int tid = threadIdx.x;
  for (int idx = tid; idx < DH_*32; idx += 256){
    int d = idx >> 5, j = idx & 31;
    rotS[d][j] = rot[(size_t)d*(NHASH_*32) + h*32 + j];
  }
  for (int idx = tid; idx < 64*DH_; idx += 256){
    int tt = idx >> 6, d = idx & 63;
    qs[tt][d] = qk[((size_t)(b*T_ + t0 + tt))*DIM_ + head*DH_ + d];
  }
  __syncthreads();
  int tt = tid >> 2, lane = tid & 3;
  int j0 = lane * 8;
  float r8[8];
  #pragma unroll
  for (int k=0;k<8;k++) r8[k] = 0.f;
  for (int d=0; d<DH_; d++){
    float q = qs[tt][d];
    #pragma unroll
    for (int k=0;k<8;k++) r8[k] += q * rotS[d][j0+k];
  }
  // local argmax in increasing global-index order (np.argmax first-occurrence)
  float best = r8[0]; int bidx = j0;
  #pragma unroll
  for (int k=1;k<8;k++){ if (r8[k] > best){ best = r8[k]; bidx = j0+k; } }
  #pragma unroll
  for (int k=0;k<8;k++){ float v = -r8[k]; if (v > best){ best = v; bidx = 32+j0+k; } }
  // merge across the 4 lanes of this token; on exact tie prefer lower index
  #pragma unroll
  for (int x=1; x<=2; x<<=1){
    float ov = __shfl_xor(best, x);
    int   oi = __shfl_xor(bidx, x);
    if (ov > best || (ov == best && oi < bidx)){ best = ov; bidx = oi; }
  }
  if (lane == 0)
    buckets[((size_t)bh*NHASH_ + h)*T_ + t0 + tt] = bidx;
}

// ---------------- stable counting sort per (bh, hash round); keys unique
__global__ __launch_bounds__(64) void k_sort(const int* __restrict__ buckets,
                                             int* __restrict__ st, int* __restrict__ p2s){
  int blk = blockIdx.x;              // BH*NHASH = 128
  int bh = blk >> 3, h = blk & 7;
  const int* bptr = buckets + ((size_t)bh*NHASH_ + h)*T_;
  __shared__ unsigned char bb[T_];
  __shared__ int offs[NB_+1];
  for (int i = threadIdx.x; i < T_; i += 64) bb[i] = (unsigned char)bptr[i];
  __syncthreads();
  int j = threadIdx.x;               // one thread per bucket bin
  int cnt = 0;
  for (int t=0;t<T_;t++) if (bb[t]==j) cnt++;
  offs[j+1] = cnt;
  __syncthreads();
  if (threadIdx.x==0){ offs[0]=0; for (int q=1;q<=NB_;q++) offs[q]+=offs[q-1]; }
  __syncthreads();
  int off = offs[j];
  size_t base = (size_t)bh*SORTN_ + (size_t)h*T_;
  for (int t=0;t<T_;t++){
    if (bb[t]==j){ st[base+off] = t; p2s[base+t] = off; off++; }
  }
}

// ---------------- chunked LSH attention (64 q x 128 k, look-one-back, self-mask)
// LDS tile is reused: first holds qk rows (scores), then fp32 V rows (PV).
template <bool OS_FP32>
__global__ __launch_bounds__(256) void k_attn(const float* __restrict__ qkbuf,
                                              const float* __restrict__ vbuf,
                                              const int* __restrict__ st,
                                              float* __restrict__ lseb,
                                              void* __restrict__ osortv){
  __shared__ float rows[128][68];      // 34.8 KB, reused qk -> V
  __shared__ float inv[128];
  __shared__ int spos[128];
  int blk = blockIdx.x;
  int bh = blk >> 9;
  int c = blk & (NCH_-1);
  int b = bh >> 3, head = bh & 7;
  int cprev = (c + NCH_ - 1) & (NCH_-1);
  int tid = threadIdx.x;
  const int* stb = st + (size_t)bh * SORTN_;
  if (tid < 128){
    int gc = (tid < 64) ? c : cprev;
    spos[tid] = stb[gc*64 + (tid & 63)];
  }
  __syncthreads();
  for (int idx = tid; idx < 128*64; idx += 256){
    int j = idx >> 6, d = idx & 63;
    rows[j][d] = qkbuf[((size_t)(b*T_ + spos[j]))*DIM_ + head*DH_ + d];
  }
  __syncthreads();
  if (tid < 128){
    const float4* rp = (const float4*)&rows[tid][0];
    float s = 0.f;
    #pragma unroll
    for (int q=0;q<16;q++){
      float4 r4 = rp[q];
      s += r4.x*r4.x + r4.y*r4.y + r4.z*r4.z + r4.w*r4.w;
    }
    inv[tid] = 1.0f / sqrtf(s);
  }
  __syncthreads();
  int i = tid >> 2, jg = tid & 3;      // 4 lanes per query row, 32 keys each
  float accj[32];
  #pragma unroll
  for (int jj=0;jj<32;jj++) accj[jj] = 0.f;
  #pragma unroll
  for (int db=0; db<4; db++){
    const float4* qp = (const float4*)&rows[i][db*16];
    float4 q0=qp[0], q1=qp[1], q2=qp[2], q3=qp[3];
    #pragma unroll
    for (int jj=0;jj<32;jj++){
      const float4* kp = (const float4*)&rows[jg*32+jj][db*16];
      float4 k0=kp[0], k1=kp[1], k2=kp[2], k3=kp[3];
      accj[jj] += q0.x*k0.x + q0.y*k0.y + q0.z*k0.z + q0.w*k0.w
                + q1.x*k1.x + q1.y*k1.y + q1.z*k1.z + q1.w*k1.w
                + q2.x*k2.x + q2.y*k2.y + q2.z*k2.z + q2.w*k2.w
                + q3.x*k3.x + q3.y*k3.y + q3.z*k3.z + q3.w*k3.w;
    }
  }
  int posq = spos[i];
  float m = -3.0e38f;
  #pragma unroll
  for (int jj=0;jj<32;jj++){
    int j = jg*32 + jj;
    float s = accj[jj] * inv[j] * 0.125f;
    if (spos[j] == posq) s = -5.0e4f;   // TOKEN_SELF_ATTN_VALUE
    accj[jj] = s;
    m = fmaxf(m, s);
  }
  m = fmaxf(m, __shfl_xor(m,1));
  m = fmaxf(m, __shfl_xor(m,2));
  float sum = 0.f;
  #pragma unroll
  for (int jj=0;jj<32;jj++){ accj[jj] = expf(accj[jj]-m); sum += accj[jj]; }
  sum += __shfl_xor(sum,1);
  sum += __shfl_xor(sum,2);
  float lse = m + logf(sum);
  if (jg == 0) lseb[(size_t)bh*SORTN_ + (size_t)c*64 + i] = lse;
  float rsum = 1.0f / sum;
  // ---- swap LDS contents: qk rows -> fp32 V rows ----
  __syncthreads();
  for (int idx = tid; idx < 128*64; idx += 256){
    int j = idx >> 6, d = idx & 63;
    rows[j][d] = vbuf[((size_t)(b*T_ + spos[j]))*DIM_ + head*DH_ + d];
  }
  __syncthreads();
  float acc[64];
  #pragma unroll
  for (int d=0;d<64;d++) acc[d]=0.f;
  #pragma unroll
  for (int jj=0;jj<32;jj++){
    float p = accj[jj] * rsum;
    int j = jg*32 + jj;
    const float4* vp = (const float4*)&rows[j][0];
    #pragma unroll
    for (int d4=0; d4<16; d4++){
      float4 v4 = vp[d4];
      int dd = d4*4;
      acc[dd+0] += p * v4.x;
      acc[dd+1] += p * v4.y;
      acc[dd+2] += p * v4.z;
      acc[dd+3] += p * v4.w;
    }
  }
  #pragma unroll
  for (int d=0; d<64; d++){
    acc[d] += __shfl_xor(acc[d], 1);
    acc[d] += __shfl_xor(acc[d], 2);
  }
  size_t ob = ((size_t)bh*SORTN_ + (size_t)c*64 + i) * 64 + jg*16;
  if (OS_FP32){
    float* osf = (float*)osortv;
    #pragma unroll
    for (int q=0;q<4;q++){
      *(float4*)&osf[ob + q*4] = make_float4(acc[jg*16+q*4+0], acc[jg*16+q*4+1],
                                             acc[jg*16+q*4+2], acc[jg*16+q*4+3]);
    }
  } else {
    ushort_t* osu = (ushort_t*)osortv;
    uint32 pk[8];
    #pragma unroll
    for (int k=0;k<8;k++){
      pk[k] = (uint32)f2bf(acc[jg*16 + 2*k]) | ((uint32)f2bf(acc[jg*16 + 2*k + 1]) << 16);
    }
    *(uint4*)&osu[ob]   = make_uint4(pk[0],pk[1],pk[2],pk[3]);
    *(uint4*)&osu[ob+8] = make_uint4(pk[4],pk[5],pk[6],pk[7]);
  }
}

// ---------------- unsort + combine hash rounds by lse softmax -> ctx (B,T,DIM)
template <bool OS_FP32>
__global__ __launch_bounds__(512) void k_combine(const float* __restrict__ lseb,
                                                 const void* __restrict__ osortv,
                                                 const int* __restrict__ p2s,
                                                 float* __restrict__ ctx){
  int row = blockIdx.x;
  int b = row >> 12, t = row & (T_-1);
  int head = threadIdx.x >> 6, d = threadIdx.x & 63;
  int bh = b*H_ + head;
  const int* pp = p2s + (size_t)bh*SORTN_;
  const float* lp = lseb + (size_t)bh*SORTN_;
  int g[NHASH_]; float l[NHASH_];
  float m = -3.0e38f;
  #pragma unroll
  for (int h=0; h<NHASH_; h++){
    int s = pp[h*T_ + t];
    g[h] = h*T_ + s;
    l[h] = lp[g[h]];
    m = fmaxf(m, l[h]);
  }
  float sum = 0.f;
  #pragma unroll
  for (int h=0; h<NHASH_; h++){ l[h] = expf(l[h]-m); sum += l[h]; }
  float rs = 1.0f/sum;
  float acc = 0.f;
  #pragma unroll
  for (int h=0; h<NHASH_; h++){
    size_t off = ((size_t)bh*SORTN_ + g[h])*64 + d;
    float ov = OS_FP32 ? ((const float*)osortv)[off]
                       : bf2f(((const ushort_t*)osortv)[off]);
    acc += l[h] * ov;
  }
  ctx[(size_t)row*DIM_ + head*DH_ + d] = acc * rs;
}

// ---------------- final head: out = xn @ Wout + bout (N=17), fp32 output
__global__ __launch_bounds__(64) void k_final(const float* __restrict__ xn,
                                              const float* __restrict__ Wout,
                                              const float* __restrict__ bout,
                                              float* __restrict__ out){
  int row = blockIdx.x;
  int n = threadIdx.x;
  if (n >= TAGS_) return;
  float acc = bout[n];
  const float* xr = xn + (size_t)row*DIM_;
  for (int d=0; d<DIM_; d++) acc += xr[d] * Wout[d*TAGS_ + n];
  out[(size_t)row*TAGS_ + n] = acc;
}

extern "C" void kernel_launch(void* const* d_in, const int* in_sizes, int n_in,
                              void* d_out, int out_size, void* d_ws, size_t ws_size,
                              hipStream_t stream){
  const int* X         = (const int*)d_in[0];
  const float* tok     = (const float*)d_in[1];
  const float* ax1     = (const float*)d_in[2];
  const float* ax2     = (const float*)d_in[3];
  const float* Wqk     = (const float*)d_in[4];
  const float* Wv      = (const float*)d_in[5];
  const float* Wo      = (const float*)d_in[6];
  const float* ln1g    = (const float*)d_in[7];
  const float* ln1b    = (const float*)d_in[8];
  const float* W1      = (const float*)d_in[9];
  const float* b1      = (const float*)d_in[10];
  const float* W2      = (const float*)d_in[11];
  const float* b2      = (const float*)d_in[12];
  const float* ln2g    = (const float*)d_in[13];
  const float* ln2b    = (const float*)d_in[14];
  const float* lnfg    = (const float*)d_in[15];
  const float* lnfb    = (const float*)d_in[16];
  const float* WoutP   = (const float*)d_in[17];
  const float* boutP   = (const float*)d_in[18];
  const float* rot     = (const float*)d_in[19];
  float* out = (float*)d_out;

  size_t NX = (size_t)ROWS_*DIM_;       // 4,194,304 floats (16 MiB)
  size_t NS = (size_t)BH_*SORTN_;       // 524,288
  float* x1 = (float*)d_ws;
  float* x2 = x1 + NX;
  float* xn = x2 + NX;                  // LN output; later reused as attention ctx
  float* qk = xn + NX;
  float* vb = qk + NX;
  float* lseb = vb + NX;
  int* buckets = (int*)(lseb + NS);
  int* st  = buckets + NS;
  int* p2s = st + NS;
  void* osort = (void*)(p2s + NS);      // fp32: 128 MiB, bf16: 64 MiB
  float* ffh = (float*)osort;           // FF hidden (64 MiB) aliases osort (disjoint lifetimes)

  // base usage before osort: 5*16 MiB + 4*2 MiB = 88 MiB
  size_t base_bytes = (5*NX + 4*NS) * sizeof(float);
  bool os_fp32 = ws_size >= base_bytes + NS*64*sizeof(float);

  k_embed<<<ROWS_, 256, 0, stream>>>(X, tok, ax1, ax2, x1, x2);
  for (int l=0; l<2; l++){
    const float* Wqk_l = Wqk + (size_t)l*DIM_*DIM_;
    const float* Wv_l  = Wv  + (size_t)l*DIM_*DIM_;
    const float* Wo_l  = Wo  + (size_t)l*DIM_*DIM_;
    const float* W1_l  = W1  + (size_t)l*DIM_*FF_;
    const float* W2_l  = W2  + (size_t)l*FF_*DIM_;
    const float* rot_l = rot + (size_t)l*DH_*NHASH_*32;
    k_ln<<<ROWS_, 256, 0, stream>>>(x2, nullptr, ln1g + l*DIM_, ln1b + l*DIM_, xn);
    k_gemm<<<dim3(DIM_/64, ROWS_/64), 256, 0, stream>>>(xn, Wqk_l, nullptr, qk, ROWS_, DIM_, DIM_, 0);
    k_gemm<<<dim3(DIM_/64, ROWS_/64), 256, 0, stream>>>(xn, Wv_l,  nullptr, vb, ROWS_, DIM_, DIM_, 0);
    k_buckets<<<dim3(T_/64, NHASH_, BH_), 256, 0, stream>>>(qk, rot_l, buckets);
    k_sort<<<BH_*NHASH_, 64, 0, stream>>>(buckets, st, p2s);
    if (os_fp32){
      k_attn<true><<<BH_*NCH_, 256, 0, stream>>>(qk, vb, st, lseb, osort);
      k_combine<true><<<ROWS_, 512, 0, stream>>>(lseb, osort, p2s, xn);
    } else {
      k_attn<false><<<BH_*NCH_, 256, 0, stream>>>(qk, vb, st, lseb, osort);
      k_combine<false><<<ROWS_, 512, 0, stream>>>(lseb, osort, p2s, xn);
    }
    k_gemm<<<dim3(DIM_/64, ROWS_/64), 256, 0, stream>>>(xn, Wo_l, nullptr, x1, ROWS_, DIM_, DIM_, 1);
    k_ln<<<ROWS_, 256, 0, stream>>>(x1, nullptr, ln2g + l*DIM_, ln2b + l*DIM_, xn);
    k_gemm<<<dim3(FF_/64, ROWS_/64), 256, 0, stream>>>(xn, W1_l, b1 + l*FF_, ffh, ROWS_, FF_, DIM_, 2);
    k_gemm<<<dim3(DIM_/64, ROWS_/64), 256, 0, stream>>>(ffh, W2_l, b2 + l*DIM_, x2, ROWS_, DIM_, FF_, 1);
  }
  k_ln<<<ROWS_, 256, 0, stream>>>(x1, x2, lnfg, lnfb, xn);
  k_final<<<ROWS_, 64, 0, stream>>>(xn, WoutP, boutP, out);
}

// Round 6
// 2208.538 us; speedup vs baseline: 2.3503x; 2.3503x over previous
//
#include <hip/hip_runtime.h>
#include <math.h>

typedef unsigned short ushort_t;
typedef unsigned int uint32;
typedef __attribute__((ext_vector_type(8))) short v8s;
typedef __attribute__((ext_vector_type(4))) float v4f;

#define B_ 2
#define T_ 4096
#define DIM_ 512
#define H_ 8
#define DH_ 64
#define BH_ 16
#define NHASH_ 8
#define NB_ 64
#define NCH_ 512
#define FF_ 2048
#define TAGS_ 17
#define ROWS_ 8192
#define SORTN_ 32768

__device__ __forceinline__ float bf2f(ushort_t u){
  return __uint_as_float(((uint32)u) << 16);
}
__device__ __forceinline__ ushort_t f2bf(float f){
  uint32 u = __float_as_uint(f);
  u += 0x7fffu + ((u >> 16) & 1u);
  return (ushort_t)(u >> 16);
}
__device__ __forceinline__ void split2(float a, ushort_t& h, ushort_t& l){
  h = f2bf(a);
  l = f2bf(a - bf2f(h));
}

// ---------------- embed: x = tok_emb[X] + axial pos, duplicated into x1,x2
__global__ __launch_bounds__(256) void k_embed(const int* __restrict__ X,
                                               const float* __restrict__ tok,
                                               const float* __restrict__ ax1,
                                               const float* __restrict__ ax2,
                                               float* __restrict__ x1, float* __restrict__ x2){
  int row = blockIdx.x;
  int t = row & (T_-1);
  int tokid = X[row];
  size_t base = (size_t)row * DIM_;
  for (int d = threadIdx.x; d < DIM_; d += 256){
    float e = tok[(size_t)tokid*DIM_ + d];
    float p = (d < 256) ? ax1[(t>>6)*256 + d] : ax2[(t&63)*256 + (d-256)];
    float v = e + p;
    x1[base+d] = v; x2[base+d] = v;
  }
}

// ---------------- layernorm; writes fp32 (Yf) or split-bf16 planes (Yh/Yl)
__global__ __launch_bounds__(256) void k_ln(const float* __restrict__ A, const float* __restrict__ Bb,
                                            const float* __restrict__ g, const float* __restrict__ be,
                                            float* __restrict__ Yf,
                                            ushort_t* __restrict__ Yh, ushort_t* __restrict__ Yl){
  int row = blockIdx.x; int tid = threadIdx.x;
  size_t base = (size_t)row * DIM_;
  float x0 = A[base+tid], x1v = A[base+tid+256];
  if (Bb){ x0 = 0.5f*(x0 + Bb[base+tid]); x1v = 0.5f*(x1v + Bb[base+tid+256]); }
  float s = x0 + x1v, sq = x0*x0 + x1v*x1v;
  for (int o=32;o>0;o>>=1){ s += __shfl_down(s,o); sq += __shfl_down(sq,o); }
  __shared__ float ls[4], lq[4], mm[2];
  if ((tid&63)==0){ ls[tid>>6]=s; lq[tid>>6]=sq; }
  __syncthreads();
  if (tid==0){
    float S=ls[0]+ls[1]+ls[2]+ls[3], Q=lq[0]+lq[1]+lq[2]+lq[3];
    float m = S*(1.0f/DIM_); float var = Q*(1.0f/DIM_) - m*m;
    mm[0]=m; mm[1]=1.0f/sqrtf(var+1e-5f);
  }
  __syncthreads();
  float m=mm[0], r=mm[1];
  float y0 = (x0 -m)*r*g[tid]     + be[tid];
  float y1 = (x1v-m)*r*g[tid+256] + be[tid+256];
  if (Yf){
    Yf[base+tid] = y0; Yf[base+tid+256] = y1;
  } else {
    ushort_t h, l;
    split2(y0, h, l); Yh[base+tid] = h;     Yl[base+tid] = l;
    split2(y1, h, l); Yh[base+tid+256] = h; Yl[base+tid+256] = l;
  }
}

// ---------------- weight pre-split + transpose: W[K][N] fp32 -> Wt_hi/lo [N][K] bf16
__global__ __launch_bounds__(256) void k_splitw(const float* __restrict__ W,
                                                ushort_t* __restrict__ Whi, ushort_t* __restrict__ Wlo,
                                                int K, int N){
  __shared__ float tile[32][33];
  int n0 = blockIdx.x*32, k0 = blockIdx.y*32;
  int tid = threadIdx.x;
  for (int idx=tid; idx<1024; idx+=256){
    int kk = idx>>5, nn = idx&31;
    tile[kk][nn] = W[(size_t)(k0+kk)*N + n0+nn];
  }
  __syncthreads();
  for (int idx=tid; idx<1024; idx+=256){
    int nn = idx>>5, kk = idx&31;
    float a = tile[kk][nn];
    ushort_t h, l; split2(a, h, l);
    size_t off = (size_t)(n0+nn)*K + k0+kk;
    Whi[off] = h; Wlo[off] = l;
  }
}

// ---------------- split-bf16 MFMA GEMM: C(MxN) = A(MxK) @ B(KxN) [+bias][gelu]
// A given as split planes [M][K]; B as split transposed planes [N][K].
// flags: 1 = += into outF (residual), 2 = gelu, 4 = split output planes
template<int BN>
__global__ __launch_bounds__(256) void k_gemm_mfma(
    const ushort_t* __restrict__ A_hi, const ushort_t* __restrict__ A_lo,
    const ushort_t* __restrict__ Bt_hi, const ushort_t* __restrict__ Bt_lo,
    const float* __restrict__ bias,
    float* __restrict__ outF,
    ushort_t* __restrict__ out_hi, ushort_t* __restrict__ out_lo,
    int M, int N, int K, int flags){
  constexpr int NT = BN/32;
  __shared__ ushort_t As[2][128*40];
  __shared__ ushort_t Bs[2][BN*40];
  int tid = threadIdx.x;
  int bn = blockIdx.x * BN, bm = blockIdx.y * 128;
  int w = tid>>6, lane = tid&63;
  int wm = w>>1, wn = w&1;
  int lr = lane&15, quad = lane>>4;
  v4f acc[4][NT];
  #pragma unroll
  for (int mt=0;mt<4;mt++)
    #pragma unroll
    for (int nt=0;nt<NT;nt++) acc[mt][nt] = (v4f){0.f,0.f,0.f,0.f};

  for (int k0=0; k0<K; k0+=32){
    // A tile: 128 rows x 32 k; one uint4 = 8 ushorts; 512 uint4 per plane
    #pragma unroll
    for (int idx = tid; idx < 512; idx += 256){
      int r = idx >> 2, qq = idx & 3;
      size_t go = (size_t)(bm+r)*K + k0 + qq*8;
      *(uint4*)&As[0][r*40 + qq*8] = *(const uint4*)(A_hi + go);
      *(uint4*)&As[1][r*40 + qq*8] = *(const uint4*)(A_lo + go);
    }
    // B tile: BN rows x 32 k; BN*4 uint4 per plane
    for (int idx = tid; idx < BN*4; idx += 256){
      int r = idx >> 2, qq = idx & 3;
      size_t go = (size_t)(bn+r)*K + k0 + qq*8;
      *(uint4*)&Bs[0][r*40 + qq*8] = *(const uint4*)(Bt_hi + go);
      *(uint4*)&Bs[1][r*40 + qq*8] = *(const uint4*)(Bt_lo + go);
    }
    __syncthreads();
    v8s fa_h[4], fa_l[4], fb_h[NT], fb_l[NT];
    #pragma unroll
    for (int mt=0;mt<4;mt++){
      int ro = (wm*64 + mt*16 + lr)*40 + quad*8;
      fa_h[mt] = *(const v8s*)&As[0][ro];
      fa_l[mt] = *(const v8s*)&As[1][ro];
    }
    #pragma unroll
    for (int nt=0;nt<NT;nt++){
      int ro = (wn*(BN/2) + nt*16 + lr)*40 + quad*8;
      fb_h[nt] = *(const v8s*)&Bs[0][ro];
      fb_l[nt] = *(const v8s*)&Bs[1][ro];
    }
    #pragma unroll
    for (int mt=0;mt<4;mt++)
      #pragma unroll
      for (int nt=0;nt<NT;nt++){
        acc[mt][nt] = __builtin_amdgcn_mfma_f32_16x16x32_bf16(fa_h[mt], fb_h[nt], acc[mt][nt], 0,0,0);
        acc[mt][nt] = __builtin_amdgcn_mfma_f32_16x16x32_bf16(fa_h[mt], fb_l[nt], acc[mt][nt], 0,0,0);
        acc[mt][nt] = __builtin_amdgcn_mfma_f32_16x16x32_bf16(fa_l[mt], fb_h[nt], acc[mt][nt], 0,0,0);
      }
    __syncthreads();
  }
  #pragma unroll
  for (int mt=0;mt<4;mt++){
    #pragma unroll
    for (int nt=0;nt<NT;nt++){
      int col = bn + wn*(BN/2) + nt*16 + lr;
      float bv = bias ? bias[col] : 0.f;
      #pragma unroll
      for (int r=0;r<4;r++){
        int row = bm + wm*64 + mt*16 + quad*4 + r;
        float v = acc[mt][nt][r] + bv;
        if (flags & 2){
          float x = v;
          float inner = 0.7978845608028654f * (x + 0.044715f*x*x*x);
          v = 0.5f*x*(1.0f + tanhf(inner));
        }
        size_t off = (size_t)row*N + col;
        if (flags & 4){
          ushort_t h, l; split2(v, h, l);
          out_hi[off] = h; out_lo[off] = l;
        } else if (flags & 1){
          outF[off] += v;
        } else {
          outF[off] = v;
        }
      }
    }
  }
}

// ---------------- LSH bucketing: argmax over [rot.qk, -rot.qk]
__global__ __launch_bounds__(256) void k_buckets(const float* __restrict__ qk,
                                                 const float* __restrict__ rot,
                                                 int* __restrict__ buckets){
  __shared__ float rotS[DH_][32];
  __shared__ float qs[64][68];
  int t0 = blockIdx.x * 64;
  int h  = blockIdx.y;
  int bh = blockIdx.z;
  int b = bh >> 3, head = bh & 7;
  int tid = threadIdx.x;
  for (int idx = tid; idx < DH_*32; idx += 256){
    int d = idx >> 5, j = idx & 31;
    rotS[d][j] = rot[(size_t)d*(NHASH_*32) + h*32 + j];
  }
  for (int idx = tid; idx < 64*DH_; idx += 256){
    int tt = idx >> 6, d = idx & 63;
    qs[tt][d] = qk[((size_t)(b*T_ + t0 + tt))*DIM_ + head*DH_ + d];
  }
  __syncthreads();
  int tt = tid >> 2, lane = tid & 3;
  int j0 = lane * 8;
  float r8[8];
  #pragma unroll
  for (int k=0;k<8;k++) r8[k] = 0.f;
  for (int d=0; d<DH_; d++){
    float q = qs[tt][d];
    #pragma unroll
    for (int k=0;k<8;k++) r8[k] += q * rotS[d][j0+k];
  }
  float best = r8[0]; int bidx = j0;
  #pragma unroll
  for (int k=1;k<8;k++){ if (r8[k] > best){ best = r8[k]; bidx = j0+k; } }
  #pragma unroll
  for (int k=0;k<8;k++){ float v = -r8[k]; if (v > best){ best = v; bidx = 32+j0+k; } }
  #pragma unroll
  for (int x=1; x<=2; x<<=1){
    float ov = __shfl_xor(best, x);
    int   oi = __shfl_xor(bidx, x);
    if (ov > best || (ov == best && oi < bidx)){ best = ov; bidx = oi; }
  }
  if (lane == 0)
    buckets[((size_t)bh*NHASH_ + h)*T_ + t0 + tt] = bidx;
}

// ---------------- stable counting sort per (bh, hash); 4-way parallel scan
__global__ __launch_bounds__(256) void k_sort(const int* __restrict__ buckets,
                                              int* __restrict__ st, int* __restrict__ p2s){
  int blk = blockIdx.x;
  int bh = blk >> 3, h = blk & 7;
  const int* bptr = buckets + ((size_t)bh*NHASH_ + h)*T_;
  __shared__ unsigned char bb[T_];
  __shared__ int cnt[4][NB_];
  __shared__ int offs[NB_];
  int tid = threadIdx.x;
  for (int i = tid; i < T_; i += 256) bb[i] = (unsigned char)bptr[i];
  __syncthreads();
  int q = tid >> 6, j = tid & 63;
  int c0 = 0;
  for (int t = q*1024; t < q*1024 + 1024; t++) c0 += (bb[t]==j) ? 1 : 0;
  cnt[q][j] = c0;
  __syncthreads();
  if (tid == 0){
    int run = 0;
    for (int jj=0; jj<NB_; jj++){
      offs[jj] = run;
      run += cnt[0][jj] + cnt[1][jj] + cnt[2][jj] + cnt[3][jj];
    }
  }
  __syncthreads();
  int off = offs[j];
  for (int qq=0; qq<q; qq++) off += cnt[qq][j];
  size_t base = (size_t)bh*SORTN_ + (size_t)h*T_;
  for (int t = q*1024; t < q*1024 + 1024; t++){
    if (bb[t]==j){ st[base+off] = t; p2s[base+t] = off; off++; }
  }
}

// ---------------- chunked LSH attention; interleaved key ownership (bank-conflict-free)
__global__ __launch_bounds__(256) void k_attn(const float* __restrict__ qkbuf,
                                              const float* __restrict__ vbuf,
                                              const int* __restrict__ st,
                                              float* __restrict__ lseb,
                                              float* __restrict__ osort, int bh0){
  __shared__ float rows[128][68];
  __shared__ float inv[128];
  __shared__ int spos[128];
  int blk = blockIdx.x;
  int hh = blk >> 9;                 // relative head slot 0..7
  int bh = bh0 + hh;
  int c = blk & (NCH_-1);
  int b = bh >> 3, head = bh & 7;
  int cprev = (c + NCH_ - 1) & (NCH_-1);
  int tid = threadIdx.x;
  const int* stb = st + (size_t)bh * SORTN_;
  if (tid < 128){
    int gc = (tid < 64) ? c : cprev;
    spos[tid] = stb[gc*64 + (tid & 63)];
  }
  __syncthreads();
  for (int idx = tid; idx < 128*64; idx += 256){
    int j = idx >> 6, d = idx & 63;
    rows[j][d] = qkbuf[((size_t)(b*T_ + spos[j]))*DIM_ + head*DH_ + d];
  }
  __syncthreads();
  if (tid < 128){
    const float4* rp = (const float4*)&rows[tid][0];
    float s = 0.f;
    #pragma unroll
    for (int q=0;q<16;q++){
      float4 r4 = rp[q];
      s += r4.x*r4.x + r4.y*r4.y + r4.z*r4.z + r4.w*r4.w;
    }
    inv[tid] = 1.0f / sqrtf(fmaxf(s, 1e-30f));
  }
  __syncthreads();
  int i = tid >> 2, jg = tid & 3;    // lane owns keys j = jj*4 + jg (interleaved)
  float accj[32];
  #pragma unroll
  for (int jj=0;jj<32;jj++) accj[jj] = 0.f;
  #pragma unroll
  for (int db=0; db<4; db++){
    const float4* qp = (const float4*)&rows[i][db*16];
    float4 q0=qp[0], q1=qp[1], q2=qp[2], q3=qp[3];
    #pragma unroll
    for (int jj=0;jj<32;jj++){
      const float4* kp = (const float4*)&rows[jj*4+jg][db*16];
      float4 k0=kp[0], k1=kp[1], k2=kp[2], k3=kp[3];
      accj[jj] += q0.x*k0.x + q0.y*k0.y + q0.z*k0.z + q0.w*k0.w
                + q1.x*k1.x + q1.y*k1.y + q1.z*k1.z + q1.w*k1.w
                + q2.x*k2.x + q2.y*k2.y + q2.z*k2.z + q2.w*k2.w
                + q3.x*k3.x + q3.y*k3.y + q3.z*k3.z + q3.w*k3.w;
    }
  }
  int posq = spos[i];
  float m = -3.0e38f;
  #pragma unroll
  for (int jj=0;jj<32;jj++){
    int j = jj*4 + jg;
    float s = accj[jj] * inv[j] * 0.125f;
    if (spos[j] == posq) s = -5.0e4f;
    accj[jj] = s;
    m = fmaxf(m, s);
  }
  m = fmaxf(m, __shfl_xor(m,1));
  m = fmaxf(m, __shfl_xor(m,2));
  float sum = 0.f;
  #pragma unroll
  for (int jj=0;jj<32;jj++){ accj[jj] = expf(accj[jj]-m); sum += accj[jj]; }
  sum += __shfl_xor(sum,1);
  sum += __shfl_xor(sum,2);
  float lse = m + logf(sum);
  if (jg == 0) lseb[(size_t)bh*SORTN_ + (size_t)c*64 + i] = lse;
  float rsum = 1.0f / sum;
  __syncthreads();
  for (int idx = tid; idx < 128*64; idx += 256){
    int j = idx >> 6, d = idx & 63;
    rows[j][d] = vbuf[((size_t)(b*T_ + spos[j]))*DIM_ + head*DH_ + d];
  }
  __syncthreads();
  float acc[64];
  #pragma unroll
  for (int d=0;d<64;d++) acc[d]=0.f;
  #pragma unroll
  for (int jj=0;jj<32;jj++){
    float p = accj[jj] * rsum;
    const float4* vp = (const float4*)&rows[jj*4+jg][0];
    #pragma unroll
    for (int d4=0; d4<16; d4++){
      float4 v4 = vp[d4];
      int dd = d4*4;
      acc[dd+0] += p * v4.x;
      acc[dd+1] += p * v4.y;
      acc[dd+2] += p * v4.z;
      acc[dd+3] += p * v4.w;
    }
  }
  #pragma unroll
  for (int d=0; d<64; d++){
    acc[d] += __shfl_xor(acc[d], 1);
    acc[d] += __shfl_xor(acc[d], 2);
  }
  size_t ob = ((size_t)hh*SORTN_ + (size_t)c*64 + i) * 64 + jg*16;
  #pragma unroll
  for (int q=0;q<4;q++){
    *(float4*)&osort[ob + q*4] = make_float4(acc[jg*16+q*4+0], acc[jg*16+q*4+1],
                                             acc[jg*16+q*4+2], acc[jg*16+q*4+3]);
  }
}

// ---------------- unsort + combine rounds; writes ctx as split planes
__global__ __launch_bounds__(512) void k_combine(const float* __restrict__ lseb,
                                                 const float* __restrict__ osort,
                                                 const int* __restrict__ p2s,
                                                 ushort_t* __restrict__ ctx_hi,
                                                 ushort_t* __restrict__ ctx_lo,
                                                 int row0){
  int row = row0 + blockIdx.x;
  int b = row >> 12, t = row & (T_-1);
  int head = threadIdx.x >> 6, d = threadIdx.x & 63;
  int bh = b*H_ + head;
  const int* pp = p2s + (size_t)bh*SORTN_;
  const float* lp = lseb + (size_t)bh*SORTN_;
  int g[NHASH_]; float l[NHASH_];
  float m = -3.0e38f;
  #pragma unroll
  for (int h=0; h<NHASH_; h++){
    int s = pp[h*T_ + t];
    g[h] = h*T_ + s;
    l[h] = lp[g[h]];
    m = fmaxf(m, l[h]);
  }
  float sum = 0.f;
  #pragma unroll
  for (int h=0; h<NHASH_; h++){ l[h] = expf(l[h]-m); sum += l[h]; }
  float rs = 1.0f/sum;
  float acc = 0.f;
  #pragma unroll
  for (int h=0; h<NHASH_; h++){
    acc += l[h] * osort[((size_t)head*SORTN_ + g[h])*64 + d];
  }
  float o = acc * rs;
  ushort_t hi, lo; split2(o, hi, lo);
  size_t off = (size_t)row*DIM_ + head*DH_ + d;
  ctx_hi[off] = hi; ctx_lo[off] = lo;
}

// ---------------- final head: one wave per row
__global__ __launch_bounds__(64) void k_final(const float* __restrict__ xn,
                                              const float* __restrict__ Wout,
                                              const float* __restrict__ bout,
                                              float* __restrict__ out){
  int row = blockIdx.x;
  int lane = threadIdx.x;
  const float* xr = xn + (size_t)row*DIM_;
  float p[TAGS_];
  #pragma unroll
  for (int n=0;n<TAGS_;n++) p[n] = 0.f;
  for (int d = lane; d < DIM_; d += 64){
    float x = xr[d];
    const float* wr = Wout + (size_t)d*TAGS_;
    #pragma unroll
    for (int n=0;n<TAGS_;n++) p[n] += x * wr[n];
  }
  #pragma unroll
  for (int n=0;n<TAGS_;n++){
    #pragma unroll
    for (int o=32;o>0;o>>=1) p[n] += __shfl_xor(p[n], o);
  }
  if (lane == 0){
    for (int n=0;n<TAGS_;n++) out[(size_t)row*TAGS_ + n] = p[n] + bout[n];
  }
}

extern "C" void kernel_launch(void* const* d_in, const int* in_sizes, int n_in,
                              void* d_out, int out_size, void* d_ws, size_t ws_size,
                              hipStream_t stream){
  const int* X         = (const int*)d_in[0];
  const float* tok     = (const float*)d_in[1];
  const float* ax1     = (const float*)d_in[2];
  const float* ax2     = (const float*)d_in[3];
  const float* Wqk     = (const float*)d_in[4];
  const float* Wv      = (const float*)d_in[5];
  const float* Wo      = (const float*)d_in[6];
  const float* ln1g    = (const float*)d_in[7];
  const float* ln1b    = (const float*)d_in[8];
  const float* W1      = (const float*)d_in[9];
  const float* b1      = (const float*)d_in[10];
  const float* W2      = (const float*)d_in[11];
  const float* b2      = (const float*)d_in[12];
  const float* ln2g    = (const float*)d_in[13];
  const float* ln2b    = (const float*)d_in[14];
  const float* lnfg    = (const float*)d_in[15];
  const float* lnfb    = (const float*)d_in[16];
  const float* WoutP   = (const float*)d_in[17];
  const float* boutP   = (const float*)d_in[18];
  const float* rot     = (const float*)d_in[19];
  float* out = (float*)d_out;

  size_t NX = (size_t)ROWS_*DIM_;          // 4,194,304
  size_t NS = (size_t)BH_*SORTN_;          // 524,288
  const size_t S3  = (size_t)DIM_*DIM_;    // 262,144
  const size_t SW1 = (size_t)DIM_*FF_;     // 1,048,576
  const size_t WL  = 6*S3 + 2*SW1 + 2*SW1; // 5,767,168 ushorts per layer

  float* x1 = (float*)d_ws;
  float* x2 = x1 + NX;
  float* qk = x2 + NX;
  float* vb = qk + NX;
  float* lseb = vb + NX;
  int* buckets = (int*)(lseb + NS);
  int* st  = buckets + NS;
  int* p2s = st + NS;
  ushort_t* act_hi = (ushort_t*)(p2s + NS);
  ushort_t* act_lo = act_hi + NX;
  ushort_t* warena = act_lo + NX;
  float* osort = (float*)(warena + 2*WL);        // 8*SORTN*64 floats = 64 MiB
  ushort_t* ffh_hi = (ushort_t*)osort;           // FF hidden split planes alias osort
  ushort_t* ffh_lo = ffh_hi + (size_t)ROWS_*FF_;

  // ---- pre-split + transpose all weights (once per launch) ----
  for (int l=0; l<2; l++){
    ushort_t* wl = warena + (size_t)l*WL;
    ushort_t* wqk_h = wl;            ushort_t* wqk_l = wqk_h + S3;
    ushort_t* wv_h  = wqk_l + S3;    ushort_t* wv_l  = wv_h + S3;
    ushort_t* wo_h  = wv_l + S3;     ushort_t* wo_l  = wo_h + S3;
    ushort_t* w1_h  = wo_l + S3;     ushort_t* w1_l  = w1_h + SW1;
    ushort_t* w2_h  = w1_l + SW1;    ushort_t* w2_l  = w2_h + SW1;
    k_splitw<<<dim3(DIM_/32, DIM_/32), 256, 0, stream>>>(Wqk + (size_t)l*S3, wqk_h, wqk_l, DIM_, DIM_);
    k_splitw<<<dim3(DIM_/32, DIM_/32), 256, 0, stream>>>(Wv  + (size_t)l*S3, wv_h,  wv_l,  DIM_, DIM_);
    k_splitw<<<dim3(DIM_/32, DIM_/32), 256, 0, stream>>>(Wo  + (size_t)l*S3, wo_h,  wo_l,  DIM_, DIM_);
    k_splitw<<<dim3(FF_/32,  DIM_/32), 256, 0, stream>>>(W1  + (size_t)l*SW1, w1_h, w1_l, DIM_, FF_);
    k_splitw<<<dim3(DIM_/32, FF_/32),  256, 0, stream>>>(W2  + (size_t)l*SW1, w2_h, w2_l, FF_, DIM_);
  }

  k_embed<<<ROWS_, 256, 0, stream>>>(X, tok, ax1, ax2, x1, x2);
  for (int l=0; l<2; l++){
    ushort_t* wl = warena + (size_t)l*WL;
    ushort_t* wqk_h = wl;            ushort_t* wqk_l = wqk_h + S3;
    ushort_t* wv_h  = wqk_l + S3;    ushort_t* wv_l  = wv_h + S3;
    ushort_t* wo_h  = wv_l + S3;     ushort_t* wo_l  = wo_h + S3;
    ushort_t* w1_h  = wo_l + S3;     ushort_t* w1_l  = w1_h + SW1;
    ushort_t* w2_h  = w1_l + SW1;    ushort_t* w2_l  = w2_h + SW1;
    const float* rot_l = rot + (size_t)l*DH_*NHASH_*32;

    k_ln<<<ROWS_, 256, 0, stream>>>(x2, nullptr, ln1g + l*DIM_, ln1b + l*DIM_, nullptr, act_hi, act_lo);
    k_gemm_mfma<64><<<dim3(DIM_/64, ROWS_/128), 256, 0, stream>>>(
        act_hi, act_lo, wqk_h, wqk_l, nullptr, qk, nullptr, nullptr, ROWS_, DIM_, DIM_, 0);
    k_gemm_mfma<64><<<dim3(DIM_/64, ROWS_/128), 256, 0, stream>>>(
        act_hi, act_lo, wv_h, wv_l, nullptr, vb, nullptr, nullptr, ROWS_, DIM_, DIM_, 0);
    k_buckets<<<dim3(T_/64, NHASH_, BH_), 256, 0, stream>>>(qk, rot_l, buckets);
    k_sort<<<BH_*NHASH_, 256, 0, stream>>>(buckets, st, p2s);
    k_attn<<<8*NCH_, 256, 0, stream>>>(qk, vb, st, lseb, osort, 0);
    k_combine<<<T_, 512, 0, stream>>>(lseb, osort, p2s, act_hi, act_lo, 0);
    k_attn<<<8*NCH_, 256, 0, stream>>>(qk, vb, st, lseb, osort, 8);
    k_combine<<<T_, 512, 0, stream>>>(lseb, osort, p2s, act_hi, act_lo, T_);
    k_gemm_mfma<64><<<dim3(DIM_/64, ROWS_/128), 256, 0, stream>>>(
        act_hi, act_lo, wo_h, wo_l, nullptr, x1, nullptr, nullptr, ROWS_, DIM_, DIM_, 1);
    k_ln<<<ROWS_, 256, 0, stream>>>(x1, nullptr, ln2g + l*DIM_, ln2b + l*DIM_, nullptr, act_hi, act_lo);
    k_gemm_mfma<128><<<dim3(FF_/128, ROWS_/128), 256, 0, stream>>>(
        act_hi, act_lo, w1_h, w1_l, b1 + l*FF_, nullptr, ffh_hi, ffh_lo, ROWS_, FF_, DIM_, 2|4);
    k_gemm_mfma<64><<<dim3(DIM_/64, ROWS_/128), 256, 0, stream>>>(
        ffh_hi, ffh_lo, w2_h, w2_l, b2 + l*DIM_, x2, nullptr, nullptr, ROWS_, DIM_, FF_, 1);
  }
  k_ln<<<ROWS_, 256, 0, stream>>>(x1, x2, lnfg, lnfb, qk, nullptr, nullptr);
  k_final<<<ROWS_, 64, 0, stream>>>(qk, WoutP, boutP, out);
}

// Round 7
// 1764.714 us; speedup vs baseline: 2.9414x; 1.2515x over previous
//
#include <hip/hip_runtime.h>
#include <math.h>

typedef unsigned short ushort_t;
typedef unsigned int uint32;
typedef __attribute__((ext_vector_type(8))) short v8s;
typedef __attribute__((ext_vector_type(4))) float v4f;

#define B_ 2
#define T_ 4096
#define DIM_ 512
#define H_ 8
#define DH_ 64
#define BH_ 16
#define NHASH_ 8
#define NB_ 64
#define NCH_ 512
#define FF_ 2048
#define TAGS_ 17
#define ROWS_ 8192
#define SORTN_ 32768

__device__ __forceinline__ float bf2f(ushort_t u){
  return __uint_as_float(((uint32)u) << 16);
}
__device__ __forceinline__ ushort_t f2bf(float f){
  uint32 u = __float_as_uint(f);
  u += 0x7fffu + ((u >> 16) & 1u);
  return (ushort_t)(u >> 16);
}
__device__ __forceinline__ void split2(float a, ushort_t& h, ushort_t& l){
  h = f2bf(a);
  l = f2bf(a - bf2f(h));
}

// ---------------- embed: x = tok_emb[X] + axial pos, duplicated into x1,x2
__global__ __launch_bounds__(256) void k_embed(const int* __restrict__ X,
                                               const float* __restrict__ tok,
                                               const float* __restrict__ ax1,
                                               const float* __restrict__ ax2,
                                               float* __restrict__ x1, float* __restrict__ x2){
  int row = blockIdx.x;
  int t = row & (T_-1);
  int tokid = X[row];
  size_t base = (size_t)row * DIM_;
  for (int d = threadIdx.x; d < DIM_; d += 256){
    float e = tok[(size_t)tokid*DIM_ + d];
    float p = (d < 256) ? ax1[(t>>6)*256 + d] : ax2[(t&63)*256 + (d-256)];
    float v = e + p;
    x1[base+d] = v; x2[base+d] = v;
  }
}

// ---------------- layernorm; writes fp32 (Yf) or split-bf16 planes (Yh/Yl)
__global__ __launch_bounds__(256) void k_ln(const float* __restrict__ A, const float* __restrict__ Bb,
                                            const float* __restrict__ g, const float* __restrict__ be,
                                            float* __restrict__ Yf,
                                            ushort_t* __restrict__ Yh, ushort_t* __restrict__ Yl){
  int row = blockIdx.x; int tid = threadIdx.x;
  size_t base = (size_t)row * DIM_;
  float x0 = A[base+tid], x1v = A[base+tid+256];
  if (Bb){ x0 = 0.5f*(x0 + Bb[base+tid]); x1v = 0.5f*(x1v + Bb[base+tid+256]); }
  float s = x0 + x1v, sq = x0*x0 + x1v*x1v;
  for (int o=32;o>0;o>>=1){ s += __shfl_down(s,o); sq += __shfl_down(sq,o); }
  __shared__ float ls[4], lq[4], mm[2];
  if ((tid&63)==0){ ls[tid>>6]=s; lq[tid>>6]=sq; }
  __syncthreads();
  if (tid==0){
    float S=ls[0]+ls[1]+ls[2]+ls[3], Q=lq[0]+lq[1]+lq[2]+lq[3];
    float m = S*(1.0f/DIM_); float var = Q*(1.0f/DIM_) - m*m;
    mm[0]=m; mm[1]=1.0f/sqrtf(var+1e-5f);
  }
  __syncthreads();
  float m=mm[0], r=mm[1];
  float y0 = (x0 -m)*r*g[tid]     + be[tid];
  float y1 = (x1v-m)*r*g[tid+256] + be[tid+256];
  if (Yf){
    Yf[base+tid] = y0; Yf[base+tid+256] = y1;
  } else {
    ushort_t h, l;
    split2(y0, h, l); Yh[base+tid] = h;     Yl[base+tid] = l;
    split2(y1, h, l); Yh[base+tid+256] = h; Yl[base+tid+256] = l;
  }
}

// ---------------- weight pre-split + transpose: W[K][N] fp32 -> Wt_hi/lo [N][K] bf16
__global__ __launch_bounds__(256) void k_splitw(const float* __restrict__ W,
                                                ushort_t* __restrict__ Whi, ushort_t* __restrict__ Wlo,
                                                int K, int N){
  __shared__ float tile[32][33];
  int n0 = blockIdx.x*32, k0 = blockIdx.y*32;
  int tid = threadIdx.x;
  for (int idx=tid; idx<1024; idx+=256){
    int kk = idx>>5, nn = idx&31;
    tile[kk][nn] = W[(size_t)(k0+kk)*N + n0+nn];
  }
  __syncthreads();
  for (int idx=tid; idx<1024; idx+=256){
    int nn = idx>>5, kk = idx&31;
    float a = tile[kk][nn];
    ushort_t h, l; split2(a, h, l);
    size_t off = (size_t)(n0+nn)*K + k0+kk;
    Whi[off] = h; Wlo[off] = l;
  }
}

// ---------------- split-bf16 MFMA GEMM: C(MxN) = A(MxK) @ B(KxN) [+bias][gelu]
// flags: 1 = += into outF (residual), 2 = gelu, 4 = split output planes
template<int BN>
__global__ __launch_bounds__(256) void k_gemm_mfma(
    const ushort_t* __restrict__ A_hi, const ushort_t* __restrict__ A_lo,
    const ushort_t* __restrict__ Bt_hi, const ushort_t* __restrict__ Bt_lo,
    const float* __restrict__ bias,
    float* __restrict__ outF,
    ushort_t* __restrict__ out_hi, ushort_t* __restrict__ out_lo,
    int M, int N, int K, int flags){
  constexpr int NT = BN/32;
  __shared__ ushort_t As[2][128*40];
  __shared__ ushort_t Bs[2][BN*40];
  int tid = threadIdx.x;
  int bn = blockIdx.x * BN, bm = blockIdx.y * 128;
  int w = tid>>6, lane = tid&63;
  int wm = w>>1, wn = w&1;
  int lr = lane&15, quad = lane>>4;
  v4f acc[4][NT];
  #pragma unroll
  for (int mt=0;mt<4;mt++)
    #pragma unroll
    for (int nt=0;nt<NT;nt++) acc[mt][nt] = (v4f){0.f,0.f,0.f,0.f};

  for (int k0=0; k0<K; k0+=32){
    #pragma unroll
    for (int idx = tid; idx < 512; idx += 256){
      int r = idx >> 2, qq = idx & 3;
      size_t go = (size_t)(bm+r)*K + k0 + qq*8;
      *(uint4*)&As[0][r*40 + qq*8] = *(const uint4*)(A_hi + go);
      *(uint4*)&As[1][r*40 + qq*8] = *(const uint4*)(A_lo + go);
    }
    for (int idx = tid; idx < BN*4; idx += 256){
      int r = idx >> 2, qq = idx & 3;
      size_t go = (size_t)(bn+r)*K + k0 + qq*8;
      *(uint4*)&Bs[0][r*40 + qq*8] = *(const uint4*)(Bt_hi + go);
      *(uint4*)&Bs[1][r*40 + qq*8] = *(const uint4*)(Bt_lo + go);
    }
    __syncthreads();
    v8s fa_h[4], fa_l[4], fb_h[NT], fb_l[NT];
    #pragma unroll
    for (int mt=0;mt<4;mt++){
      int ro = (wm*64 + mt*16 + lr)*40 + quad*8;
      fa_h[mt] = *(const v8s*)&As[0][ro];
      fa_l[mt] = *(const v8s*)&As[1][ro];
    }
    #pragma unroll
    for (int nt=0;nt<NT;nt++){
      int ro = (wn*(BN/2) + nt*16 + lr)*40 + quad*8;
      fb_h[nt] = *(const v8s*)&Bs[0][ro];
      fb_l[nt] = *(const v8s*)&Bs[1][ro];
    }
    #pragma unroll
    for (int mt=0;mt<4;mt++)
      #pragma unroll
      for (int nt=0;nt<NT;nt++){
        acc[mt][nt] = __builtin_amdgcn_mfma_f32_16x16x32_bf16(fa_h[mt], fb_h[nt], acc[mt][nt], 0,0,0);
        acc[mt][nt] = __builtin_amdgcn_mfma_f32_16x16x32_bf16(fa_h[mt], fb_l[nt], acc[mt][nt], 0,0,0);
        acc[mt][nt] = __builtin_amdgcn_mfma_f32_16x16x32_bf16(fa_l[mt], fb_h[nt], acc[mt][nt], 0,0,0);
      }
    __syncthreads();
  }
  #pragma unroll
  for (int mt=0;mt<4;mt++){
    #pragma unroll
    for (int nt=0;nt<NT;nt++){
      int col = bn + wn*(BN/2) + nt*16 + lr;
      float bv = bias ? bias[col] : 0.f;
      #pragma unroll
      for (int r=0;r<4;r++){
        int row = bm + wm*64 + mt*16 + quad*4 + r;
        float v = acc[mt][nt][r] + bv;
        if (flags & 2){
          float x = v;
          float inner = 0.7978845608028654f * (x + 0.044715f*x*x*x);
          v = 0.5f*x*(1.0f + tanhf(inner));
        }
        size_t off = (size_t)row*N + col;
        if (flags & 4){
          ushort_t h, l; split2(v, h, l);
          out_hi[off] = h; out_lo[off] = l;
        } else if (flags & 1){
          outF[off] += v;
        } else {
          outF[off] = v;
        }
      }
    }
  }
}

// ---------------- LSH bucketing: argmax over [rot.qk, -rot.qk]
__global__ __launch_bounds__(256) void k_buckets(const float* __restrict__ qk,
                                                 const float* __restrict__ rot,
                                                 int* __restrict__ buckets){
  __shared__ float rotS[DH_][32];
  __shared__ float qs[64][68];
  int t0 = blockIdx.x * 64;
  int h  = blockIdx.y;
  int bh = blockIdx.z;
  int b = bh >> 3, head = bh & 7;
  int tid = threadIdx.x;
  for (int idx = tid; idx < DH_*32; idx += 256){
    int d = idx >> 5, j = idx & 31;
    rotS[d][j] = rot[(size_t)d*(NHASH_*32) + h*32 + j];
  }
  for (int idx = tid; idx < 64*DH_; idx += 256){
    int tt = idx >> 6, d = idx & 63;
    qs[tt][d] = qk[((size_t)(b*T_ + t0 + tt))*DIM_ + head*DH_ + d];
  }
  __syncthreads();
  int tt = tid >> 2, lane = tid & 3;
  int j0 = lane * 8;
  float r8[8];
  #pragma unroll
  for (int k=0;k<8;k++) r8[k] = 0.f;
  for (int d=0; d<DH_; d++){
    float q = qs[tt][d];
    #pragma unroll
    for (int k=0;k<8;k++) r8[k] += q * rotS[d][j0+k];
  }
  float best = r8[0]; int bidx = j0;
  #pragma unroll
  for (int k=1;k<8;k++){ if (r8[k] > best){ best = r8[k]; bidx = j0+k; } }
  #pragma unroll
  for (int k=0;k<8;k++){ float v = -r8[k]; if (v > best){ best = v; bidx = 32+j0+k; } }
  #pragma unroll
  for (int x=1; x<=2; x<<=1){
    float ov = __shfl_xor(best, x);
    int   oi = __shfl_xor(bidx, x);
    if (ov > best || (ov == best && oi < bidx)){ best = ov; bidx = oi; }
  }
  if (lane == 0)
    buckets[((size_t)bh*NHASH_ + h)*T_ + t0 + tt] = bidx;
}

// ---------------- stable counting sort per (bh, hash); 4-way parallel scan
__global__ __launch_bounds__(256) void k_sort(const int* __restrict__ buckets,
                                              int* __restrict__ st){
  int blk = blockIdx.x;
  int bh = blk >> 3, h = blk & 7;
  const int* bptr = buckets + ((size_t)bh*NHASH_ + h)*T_;
  __shared__ unsigned char bb[T_];
  __shared__ int cnt[4][NB_];
  __shared__ int offs[NB_];
  int tid = threadIdx.x;
  for (int i = tid; i < T_; i += 256) bb[i] = (unsigned char)bptr[i];
  __syncthreads();
  int q = tid >> 6, j = tid & 63;
  int c0 = 0;
  for (int t = q*1024; t < q*1024 + 1024; t++) c0 += (bb[t]==j) ? 1 : 0;
  cnt[q][j] = c0;
  __syncthreads();
  if (tid == 0){
    int run = 0;
    for (int jj=0; jj<NB_; jj++){
      offs[jj] = run;
      run += cnt[0][jj] + cnt[1][jj] + cnt[2][jj] + cnt[3][jj];
    }
  }
  __syncthreads();
  int off = offs[j];
  for (int qq=0; qq<q; qq++) off += cnt[qq][j];
  size_t base = (size_t)bh*SORTN_ + (size_t)h*T_;
  for (int t = q*1024; t < q*1024 + 1024; t++){
    if (bb[t]==j){ st[base+off] = t; off++; }
  }
}

// ---------------- chunked LSH attention via split-bf16 MFMA (64q x 128k x 64d)
// Output scattered directly to unsorted (hh, hash, t) layout (no undo pass).
__global__ __launch_bounds__(256) void k_attn(const float* __restrict__ qkbuf,
                                              const float* __restrict__ vbuf,
                                              const int* __restrict__ st,
                                              float* __restrict__ lse_un,
                                              float* __restrict__ o_un, int bh0){
  __shared__ ushort_t tileh[128*72];   // hi plane: QK rows -> P -> Vt
  __shared__ ushort_t tilel[128*72];   // lo plane
  __shared__ float nrm[128];           // |k|^2 then 1/|k|
  __shared__ int spos[128];
  int blk = blockIdx.x;
  int hh = blk >> 9;                   // head slot 0..7 within this half
  int bh = bh0 + hh;
  int c = blk & (NCH_-1);
  int h = c >> 6;                      // hash round of this chunk
  int b = bh >> 3, head = bh & 7;
  int cprev = (c + NCH_ - 1) & (NCH_-1);
  int tid = threadIdx.x;
  const int* stb = st + (size_t)bh * SORTN_;
  if (tid < 128){
    int gc = (tid < 64) ? c : cprev;
    spos[tid] = stb[gc*64 + (tid & 63)];
    nrm[tid] = 0.f;
  }
  __syncthreads();
  // stage QK rows as split planes + accumulate row norms
  for (int idx = tid; idx < 128*16; idx += 256){
    int j = idx >> 4, d4 = (idx & 15) * 4;
    const float* src = qkbuf + ((size_t)(b*T_ + spos[j]))*DIM_ + head*DH_ + d4;
    float4 v = *(const float4*)src;
    int o = j*72 + d4;
    ushort_t h0,l0,h1,l1,h2,l2,h3,l3;
    split2(v.x,h0,l0); split2(v.y,h1,l1); split2(v.z,h2,l2); split2(v.w,h3,l3);
    tileh[o+0]=h0; tileh[o+1]=h1; tileh[o+2]=h2; tileh[o+3]=h3;
    tilel[o+0]=l0; tilel[o+1]=l1; tilel[o+2]=l2; tilel[o+3]=l3;
    atomicAdd(&nrm[j], v.x*v.x + v.y*v.y + v.z*v.z + v.w*v.w);
  }
  __syncthreads();
  if (tid < 128) nrm[tid] = 1.0f / sqrtf(fmaxf(nrm[tid], 1e-30f));
  int w = tid >> 6, lane = tid & 63;
  int lr = lane & 15, quad = lane >> 4;
  __syncthreads();
  // S = Qraw(64x64) x Kraw^T(128x64): wave w owns q rows w*16..+15
  v4f sacc[8];
  #pragma unroll
  for (int nt=0;nt<8;nt++) sacc[nt] = (v4f){0.f,0.f,0.f,0.f};
  #pragma unroll
  for (int ks=0; ks<2; ks++){
    int ao = (w*16 + lr)*72 + ks*32 + quad*8;
    v8s fah = *(const v8s*)&tileh[ao];
    v8s fal = *(const v8s*)&tilel[ao];
    #pragma unroll
    for (int nt=0; nt<8; nt++){
      int bo = (nt*16 + lr)*72 + ks*32 + quad*8;
      v8s fbh = *(const v8s*)&tileh[bo];
      v8s fbl = *(const v8s*)&tilel[bo];
      sacc[nt] = __builtin_amdgcn_mfma_f32_16x16x32_bf16(fah, fbh, sacc[nt],0,0,0);
      sacc[nt] = __builtin_amdgcn_mfma_f32_16x16x32_bf16(fah, fbl, sacc[nt],0,0,0);
      sacc[nt] = __builtin_amdgcn_mfma_f32_16x16x32_bf16(fal, fbh, sacc[nt],0,0,0);
    }
  }
  // C layout: row = quad*4+r (within wave tile), col = nt*16+lr
  int q0 = w*16 + quad*4;
  int pq[4];
  #pragma unroll
  for (int r=0;r<4;r++) pq[r] = spos[q0 + r];
  float mrow[4] = {-3e38f,-3e38f,-3e38f,-3e38f};
  #pragma unroll
  for (int nt=0;nt<8;nt++){
    int j = nt*16 + lr;
    float sc = nrm[j] * 0.125f;
    int pk = spos[j];
    #pragma unroll
    for (int r=0;r<4;r++){
      float s = sacc[nt][r] * sc;
      if (pk == pq[r]) s = -5.0e4f;
      sacc[nt][r] = s;
      mrow[r] = fmaxf(mrow[r], s);
    }
  }
  #pragma unroll
  for (int r=0;r<4;r++){
    #pragma unroll
    for (int x=1;x<=8;x<<=1) mrow[r] = fmaxf(mrow[r], __shfl_xor(mrow[r], x));
  }
  float srow[4] = {0.f,0.f,0.f,0.f};
  #pragma unroll
  for (int nt=0;nt<8;nt++){
    #pragma unroll
    for (int r=0;r<4;r++){
      float e = expf(sacc[nt][r] - mrow[r]);
      sacc[nt][r] = e;
      srow[r] += e;
    }
  }
  #pragma unroll
  for (int r=0;r<4;r++){
    #pragma unroll
    for (int x=1;x<=8;x<<=1) srow[r] += __shfl_xor(srow[r], x);
  }
  size_t obase = ((size_t)(hh*NHASH_ + h))*T_;
  if (lr == 0){
    #pragma unroll
    for (int r=0;r<4;r++)
      lse_un[obase + pq[r]] = mrow[r] + logf(srow[r]);
  }
  float rs[4];
  #pragma unroll
  for (int r=0;r<4;r++) rs[r] = 1.0f / srow[r];
  __syncthreads();
  // P round-trip: Ps[64][136] split planes
  #pragma unroll
  for (int nt=0;nt<8;nt++){
    #pragma unroll
    for (int r=0;r<4;r++){
      float p = sacc[nt][r] * rs[r];
      ushort_t ph, pl; split2(p, ph, pl);
      int o = (q0 + r)*136 + nt*16 + lr;
      tileh[o] = ph; tilel[o] = pl;
    }
  }
  __syncthreads();
  v8s pah[4], pal[4];
  #pragma unroll
  for (int ks=0; ks<4; ks++){
    int ao = (w*16 + lr)*136 + ks*32 + quad*8;
    pah[ks] = *(const v8s*)&tileh[ao];
    pal[ks] = *(const v8s*)&tilel[ao];
  }
  __syncthreads();
  // stage V transposed: Vt[64][136] split planes
  for (int idx = tid; idx < 128*16; idx += 256){
    int j = idx >> 4, d4 = (idx & 15) * 4;
    const float* src = vbuf + ((size_t)(b*T_ + spos[j]))*DIM_ + head*DH_ + d4;
    float4 v = *(const float4*)src;
    ushort_t hx, lx;
    split2(v.x,hx,lx); tileh[(d4+0)*136 + j]=hx; tilel[(d4+0)*136 + j]=lx;
    split2(v.y,hx,lx); tileh[(d4+1)*136 + j]=hx; tilel[(d4+1)*136 + j]=lx;
    split2(v.z,hx,lx); tileh[(d4+2)*136 + j]=hx; tilel[(d4+2)*136 + j]=lx;
    split2(v.w,hx,lx); tileh[(d4+3)*136 + j]=hx; tilel[(d4+3)*136 + j]=lx;
  }
  __syncthreads();
  // O = P(64x128) x V(128x64)
  v4f oacc[4];
  #pragma unroll
  for (int nt=0;nt<4;nt++) oacc[nt] = (v4f){0.f,0.f,0.f,0.f};
  #pragma unroll
  for (int ks=0; ks<4; ks++){
    #pragma unroll
    for (int nt=0; nt<4; nt++){
      int bo = (nt*16 + lr)*136 + ks*32 + quad*8;
      v8s vbh = *(const v8s*)&tileh[bo];
      v8s vbl = *(const v8s*)&tilel[bo];
      oacc[nt] = __builtin_amdgcn_mfma_f32_16x16x32_bf16(pah[ks], vbh, oacc[nt],0,0,0);
      oacc[nt] = __builtin_amdgcn_mfma_f32_16x16x32_bf16(pah[ks], vbl, oacc[nt],0,0,0);
      oacc[nt] = __builtin_amdgcn_mfma_f32_16x16x32_bf16(pal[ks], vbh, oacc[nt],0,0,0);
    }
  }
  // scatter O rows to unsorted layout (position = spos[q])
  #pragma unroll
  for (int r=0;r<4;r++){
    size_t rowoff = (obase + pq[r])*64;
    #pragma unroll
    for (int nt=0;nt<4;nt++){
      o_un[rowoff + nt*16 + lr] = oacc[nt][r];
    }
  }
}

// ---------------- combine hash rounds (coalesced; no unsort gather needed)
__global__ __launch_bounds__(512) void k_combine(const float* __restrict__ lse_un,
                                                 const float* __restrict__ o_un,
                                                 ushort_t* __restrict__ ctx_hi,
                                                 ushort_t* __restrict__ ctx_lo,
                                                 int row0){
  int row = row0 + blockIdx.x;
  int t = row & (T_-1);
  int head = threadIdx.x >> 6, d = threadIdx.x & 63;
  float l[NHASH_];
  float m = -3.0e38f;
  #pragma unroll
  for (int h=0; h<NHASH_; h++){
    l[h] = lse_un[((size_t)(head*NHASH_ + h))*T_ + t];
    m = fmaxf(m, l[h]);
  }
  float sum = 0.f;
  #pragma unroll
  for (int h=0; h<NHASH_; h++){ l[h] = expf(l[h]-m); sum += l[h]; }
  float rsv = 1.0f/sum;
  float acc = 0.f;
  #pragma unroll
  for (int h=0; h<NHASH_; h++){
    acc += l[h] * o_un[(((size_t)(head*NHASH_ + h))*T_ + t)*64 + d];
  }
  float o = acc * rsv;
  ushort_t hi, lo; split2(o, hi, lo);
  size_t off = (size_t)row*DIM_ + head*DH_ + d;
  ctx_hi[off] = hi; ctx_lo[off] = lo;
}

// ---------------- final head: one wave per row
__global__ __launch_bounds__(64) void k_final(const float* __restrict__ xn,
                                              const float* __restrict__ Wout,
                                              const float* __restrict__ bout,
                                              float* __restrict__ out){
  int row = blockIdx.x;
  int lane = threadIdx.x;
  const float* xr = xn + (size_t)row*DIM_;
  float p[TAGS_];
  #pragma unroll
  for (int n=0;n<TAGS_;n++) p[n] = 0.f;
  for (int d = lane; d < DIM_; d += 64){
    float x = xr[d];
    const float* wr = Wout + (size_t)d*TAGS_;
    #pragma unroll
    for (int n=0;n<TAGS_;n++) p[n] += x * wr[n];
  }
  #pragma unroll
  for (int n=0;n<TAGS_;n++){
    #pragma unroll
    for (int o=32;o>0;o>>=1) p[n] += __shfl_xor(p[n], o);
  }
  if (lane == 0){
    for (int n=0;n<TAGS_;n++) out[(size_t)row*TAGS_ + n] = p[n] + bout[n];
  }
}

extern "C" void kernel_launch(void* const* d_in, const int* in_sizes, int n_in,
                              void* d_out, int out_size, void* d_ws, size_t ws_size,
                              hipStream_t stream){
  const int* X         = (const int*)d_in[0];
  const float* tok     = (const float*)d_in[1];
  const float* ax1     = (const float*)d_in[2];
  const float* ax2     = (const float*)d_in[3];
  const float* Wqk     = (const float*)d_in[4];
  const float* Wv      = (const float*)d_in[5];
  const float* Wo      = (const float*)d_in[6];
  const float* ln1g    = (const float*)d_in[7];
  const float* ln1b    = (const float*)d_in[8];
  const float* W1      = (const float*)d_in[9];
  const float* b1      = (const float*)d_in[10];
  const float* W2      = (const float*)d_in[11];
  const float* b2      = (const float*)d_in[12];
  const float* ln2g    = (const float*)d_in[13];
  const float* ln2b    = (const float*)d_in[14];
  const float* lnfg    = (const float*)d_in[15];
  const float* lnfb    = (const float*)d_in[16];
  const float* WoutP   = (const float*)d_in[17];
  const float* boutP   = (const float*)d_in[18];
  const float* rot     = (const float*)d_in[19];
  float* out = (float*)d_out;

  size_t NX = (size_t)ROWS_*DIM_;          // 4,194,304
  size_t NS = (size_t)BH_*SORTN_;          // 524,288
  const size_t S3  = (size_t)DIM_*DIM_;
  const size_t SW1 = (size_t)DIM_*FF_;
  const size_t WL  = 6*S3 + 2*SW1 + 2*SW1; // ushorts per layer

  float* x1 = (float*)d_ws;
  float* x2 = x1 + NX;
  float* qk = x2 + NX;
  float* vb = qk + NX;
  float* lse_un = vb + NX;                 // 8*NHASH*T = 262,144 floats used
  int* buckets = (int*)(lse_un + NS);
  int* st  = buckets + NS;
  ushort_t* act_hi = (ushort_t*)(st + NS);
  ushort_t* act_lo = act_hi + NX;
  ushort_t* warena = act_lo + NX;
  float* o_un = (float*)(warena + 2*WL);   // 8*NHASH*T*64 floats = 64 MiB
  ushort_t* ffh_hi = (ushort_t*)o_un;      // FF hidden split planes alias o_un
  ushort_t* ffh_lo = ffh_hi + (size_t)ROWS_*FF_;

  for (int l=0; l<2; l++){
    ushort_t* wl = warena + (size_t)l*WL;
    ushort_t* wqk_h = wl;            ushort_t* wqk_l = wqk_h + S3;
    ushort_t* wv_h  = wqk_l + S3;    ushort_t* wv_l  = wv_h + S3;
    ushort_t* wo_h  = wv_l + S3;     ushort_t* wo_l  = wo_h + S3;
    ushort_t* w1_h  = wo_l + S3;     ushort_t* w1_l  = w1_h + SW1;
    ushort_t* w2_h  = w1_l + SW1;    ushort_t* w2_l  = w2_h + SW1;
    k_splitw<<<dim3(DIM_/32, DIM_/32), 256, 0, stream>>>(Wqk + (size_t)l*S3, wqk_h, wqk_l, DIM_, DIM_);
    k_splitw<<<dim3(DIM_/32, DIM_/32), 256, 0, stream>>>(Wv  + (size_t)l*S3, wv_h,  wv_l,  DIM_, DIM_);
    k_splitw<<<dim3(DIM_/32, DIM_/32), 256, 0, stream>>>(Wo  + (size_t)l*S3, wo_h,  wo_l,  DIM_, DIM_);
    k_splitw<<<dim3(FF_/32,  DIM_/32), 256, 0, stream>>>(W1  + (size_t)l*SW1, w1_h, w1_l, DIM_, FF_);
    k_splitw<<<dim3(DIM_/32, FF_/32),  256, 0, stream>>>(W2  + (size_t)l*SW1, w2_h, w2_l, FF_, DIM_);
  }

  k_embed<<<ROWS_, 256, 0, stream>>>(X, tok, ax1, ax2, x1, x2);
  for (int l=0; l<2; l++){
    ushort_t* wl = warena + (size_t)l*WL;
    ushort_t* wqk_h = wl;            ushort_t* wqk_l = wqk_h + S3;
    ushort_t* wv_h  = wqk_l + S3;    ushort_t* wv_l  = wv_h + S3;
    ushort_t* wo_h  = wv_l + S3;     ushort_t* wo_l  = wo_h + S3;
    ushort_t* w1_h  = wo_l + S3;     ushort_t* w1_l  = w1_h + SW1;
    ushort_t* w2_h  = w1_l + SW1;    ushort_t* w2_l  = w2_h + SW1;
    const float* rot_l = rot + (size_t)l*DH_*NHASH_*32;

    k_ln<<<ROWS_, 256, 0, stream>>>(x2, nullptr, ln1g + l*DIM_, ln1b + l*DIM_, nullptr, act_hi, act_lo);
    k_gemm_mfma<64><<<dim3(DIM_/64, ROWS_/128), 256, 0, stream>>>(
        act_hi, act_lo, wqk_h, wqk_l, nullptr, qk, nullptr, nullptr, ROWS_, DIM_, DIM_, 0);
    k_gemm_mfma<64><<<dim3(DIM_/64, ROWS_/128), 256, 0, stream>>>(
        act_hi, act_lo, wv_h, wv_l, nullptr, vb, nullptr, nullptr, ROWS_, DIM_, DIM_, 0);
    k_buckets<<<dim3(T_/64, NHASH_, BH_), 256, 0, stream>>>(qk, rot_l, buckets);
    k_sort<<<BH_*NHASH_, 256, 0, stream>>>(buckets, st);
    k_attn<<<8*NCH_, 256, 0, stream>>>(qk, vb, st, lse_un, o_un, 0);
    k_combine<<<T_, 512, 0, stream>>>(lse_un, o_un, act_hi, act_lo, 0);
    k_attn<<<8*NCH_, 256, 0, stream>>>(qk, vb, st, lse_un, o_un, 8);
    k_combine<<<T_, 512, 0, stream>>>(lse_un, o_un, act_hi, act_lo, T_);
    k_gemm_mfma<64><<<dim3(DIM_/64, ROWS_/128), 256, 0, stream>>>(
        act_hi, act_lo, wo_h, wo_l, nullptr, x1, nullptr, nullptr, ROWS_, DIM_, DIM_, 1);
    k_ln<<<ROWS_, 256, 0, stream>>>(x1, nullptr, ln2g + l*DIM_, ln2b + l*DIM_, nullptr, act_hi, act_lo);
    k_gemm_mfma<128><<<dim3(FF_/128, ROWS_/128), 256, 0, stream>>>(
        act_hi, act_lo, w1_h, w1_l, b1 + l*FF_, nullptr, ffh_hi, ffh_lo, ROWS_, FF_, DIM_, 2|4);
    k_gemm_mfma<64><<<dim3(DIM_/64, ROWS_/128), 256, 0, stream>>>(
        ffh_hi, ffh_lo, w2_h, w2_l, b2 + l*DIM_, x2, nullptr, nullptr, ROWS_, DIM_, FF_, 1);
  }
  k_ln<<<ROWS_, 256, 0, stream>>>(x1, x2, lnfg, lnfb, qk, nullptr, nullptr);
  k_final<<<ROWS_, 64, 0, stream>>>(qk, WoutP, boutP, out);
}

// Round 8
// 1510.362 us; speedup vs baseline: 3.4368x; 1.1684x over previous
//
#include <hip/hip_runtime.h>
#include <math.h>

typedef unsigned short ushort_t;
typedef unsigned int uint32;
typedef __attribute__((ext_vector_type(8))) short v8s;
typedef __attribute__((ext_vector_type(4))) float v4f;

#define B_ 2
#define T_ 4096
#define DIM_ 512
#define H_ 8
#define DH_ 64
#define BH_ 16
#define NHASH_ 8
#define NB_ 64
#define NCH_ 512
#define FF_ 2048
#define TAGS_ 17
#define ROWS_ 8192
#define SORTN_ 32768
#define QV_N 1024

__device__ __forceinline__ float bf2f(ushort_t u){
  return __uint_as_float(((uint32)u) << 16);
}
__device__ __forceinline__ ushort_t f2bf(float f){
  uint32 u = __float_as_uint(f);
  u += 0x7fffu + ((u >> 16) & 1u);
  return (ushort_t)(u >> 16);
}
__device__ __forceinline__ void split2(float a, ushort_t& h, ushort_t& l){
  h = f2bf(a);
  l = f2bf(a - bf2f(h));
}
// async global->LDS, 16B per lane; LDS dest = base + lane*16 (wave-uniform base)
__device__ __forceinline__ void gl16(const ushort_t* g, ushort_t* l){
  __builtin_amdgcn_global_load_lds(
      (const __attribute__((address_space(1))) unsigned int*)g,
      (__attribute__((address_space(3))) unsigned int*)l, 16, 0, 0);
}

// ---------------- embed
__global__ __launch_bounds__(256) void k_embed(const int* __restrict__ X,
                                               const float* __restrict__ tok,
                                               const float* __restrict__ ax1,
                                               const float* __restrict__ ax2,
                                               float* __restrict__ x1, float* __restrict__ x2){
  int row = blockIdx.x;
  int t = row & (T_-1);
  int tokid = X[row];
  size_t base = (size_t)row * DIM_;
  for (int d = threadIdx.x; d < DIM_; d += 256){
    float e = tok[(size_t)tokid*DIM_ + d];
    float p = (d < 256) ? ax1[(t>>6)*256 + d] : ax2[(t&63)*256 + (d-256)];
    float v = e + p;
    x1[base+d] = v; x2[base+d] = v;
  }
}

// ---------------- layernorm; writes fp32 (Yf) or split planes (Yh/Yl)
__global__ __launch_bounds__(256) void k_ln(const float* __restrict__ A, const float* __restrict__ Bb,
                                            const float* __restrict__ g, const float* __restrict__ be,
                                            float* __restrict__ Yf,
                                            ushort_t* __restrict__ Yh, ushort_t* __restrict__ Yl){
  int row = blockIdx.x; int tid = threadIdx.x;
  size_t base = (size_t)row * DIM_;
  float x0 = A[base+tid], x1v = A[base+tid+256];
  if (Bb){ x0 = 0.5f*(x0 + Bb[base+tid]); x1v = 0.5f*(x1v + Bb[base+tid+256]); }
  float s = x0 + x1v, sq = x0*x0 + x1v*x1v;
  for (int o=32;o>0;o>>=1){ s += __shfl_down(s,o); sq += __shfl_down(sq,o); }
  __shared__ float ls[4], lq[4], mm[2];
  if ((tid&63)==0){ ls[tid>>6]=s; lq[tid>>6]=sq; }
  __syncthreads();
  if (tid==0){
    float S=ls[0]+ls[1]+ls[2]+ls[3], Q=lq[0]+lq[1]+lq[2]+lq[3];
    float m = S*(1.0f/DIM_); float var = Q*(1.0f/DIM_) - m*m;
    mm[0]=m; mm[1]=1.0f/sqrtf(var+1e-5f);
  }
  __syncthreads();
  float m=mm[0], r=mm[1];
  float y0 = (x0 -m)*r*g[tid]     + be[tid];
  float y1 = (x1v-m)*r*g[tid+256] + be[tid+256];
  if (Yf){
    Yf[base+tid] = y0; Yf[base+tid+256] = y1;
  } else {
    ushort_t h, l;
    split2(y0, h, l); Yh[base+tid] = h;     Yl[base+tid] = l;
    split2(y1, h, l); Yh[base+tid+256] = h; Yl[base+tid+256] = l;
  }
}

// ---------------- weight pre-split + transpose
__global__ __launch_bounds__(256) void k_splitw(const float* __restrict__ W,
                                                ushort_t* __restrict__ Whi, ushort_t* __restrict__ Wlo,
                                                int K, int N){
  __shared__ float tile[32][33];
  int n0 = blockIdx.x*32, k0 = blockIdx.y*32;
  int tid = threadIdx.x;
  for (int idx=tid; idx<1024; idx+=256){
    int kk = idx>>5, nn = idx&31;
    tile[kk][nn] = W[(size_t)(k0+kk)*N + n0+nn];
  }
  __syncthreads();
  for (int idx=tid; idx<1024; idx+=256){
    int nn = idx>>5, kk = idx&31;
    float a = tile[kk][nn];
    ushort_t h, l; split2(a, h, l);
    size_t off = (size_t)(n0+nn)*K + k0+kk;
    Whi[off] = h; Wlo[off] = l;
  }
}

// ---------------- split-bf16 MFMA GEMM, m97-style: 128x128 block, BK=32,
// global_load_lds staging, unpadded stride-32 LDS.
// flags: 1 = += into outF, 2 = gelu, 4 = split output planes
__global__ __launch_bounds__(256) void k_gemm_mfma(
    const ushort_t* __restrict__ A_hi, const ushort_t* __restrict__ A_lo,
    const ushort_t* __restrict__ Bt_hi, const ushort_t* __restrict__ Bt_lo,
    const float* __restrict__ bias,
    float* __restrict__ outF,
    ushort_t* __restrict__ out_hi, ushort_t* __restrict__ out_lo,
    int M, int N, int K, int flags){
  __shared__ ushort_t As[2][128*32];
  __shared__ ushort_t Bs[2][128*32];
  int tid = threadIdx.x;
  int bn = blockIdx.x * 128, bm = blockIdx.y * 128;
  int w = tid>>6, lane = tid&63;
  int wm = w>>1, wn = w&1;
  int lr = lane&15, quad = lane>>4;
  int lrow = lane>>2, lcol = (lane&3)*8;
  v4f acc[4][4];
  #pragma unroll
  for (int mt=0;mt<4;mt++)
    #pragma unroll
    for (int nt=0;nt<4;nt++) acc[mt][nt] = (v4f){0.f,0.f,0.f,0.f};

  for (int k0=0; k0<K; k0+=32){
    #pragma unroll
    for (int i=0;i<2;i++){
      int cr = i*64 + w*16 + lrow;               // tile row this lane stages
      int lb = (i*64 + w*16)*32;                 // wave-uniform LDS base (ushorts)
      size_t goA = (size_t)(bm+cr)*K + k0 + lcol;
      size_t goB = (size_t)(bn+cr)*K + k0 + lcol;
      gl16(A_hi + goA, &As[0][lb]);
      gl16(A_lo + goA, &As[1][lb]);
      gl16(Bt_hi + goB, &Bs[0][lb]);
      gl16(Bt_lo + goB, &Bs[1][lb]);
    }
    __syncthreads();
    v8s fa_h[4], fa_l[4], fb_h[4], fb_l[4];
    #pragma unroll
    for (int mt=0;mt<4;mt++){
      int ro = (wm*64 + mt*16 + lr)*32 + quad*8;
      fa_h[mt] = *(const v8s*)&As[0][ro];
      fa_l[mt] = *(const v8s*)&As[1][ro];
    }
    #pragma unroll
    for (int nt=0;nt<4;nt++){
      int ro = (wn*64 + nt*16 + lr)*32 + quad*8;
      fb_h[nt] = *(const v8s*)&Bs[0][ro];
      fb_l[nt] = *(const v8s*)&Bs[1][ro];
    }
    #pragma unroll
    for (int mt=0;mt<4;mt++)
      #pragma unroll
      for (int nt=0;nt<4;nt++){
        acc[mt][nt] = __builtin_amdgcn_mfma_f32_16x16x32_bf16(fa_h[mt], fb_h[nt], acc[mt][nt], 0,0,0);
        acc[mt][nt] = __builtin_amdgcn_mfma_f32_16x16x32_bf16(fa_h[mt], fb_l[nt], acc[mt][nt], 0,0,0);
        acc[mt][nt] = __builtin_amdgcn_mfma_f32_16x16x32_bf16(fa_l[mt], fb_h[nt], acc[mt][nt], 0,0,0);
      }
    __syncthreads();
  }
  #pragma unroll
  for (int mt=0;mt<4;mt++){
    #pragma unroll
    for (int nt=0;nt<4;nt++){
      int col = bn + wn*64 + nt*16 + lr;
      float bv = bias ? bias[col] : 0.f;
      #pragma unroll
      for (int r=0;r<4;r++){
        int row = bm + wm*64 + mt*16 + quad*4 + r;
        float v = acc[mt][nt][r] + bv;
        if (flags & 2){
          float x = v;
          float inner = 0.7978845608028654f * (x + 0.044715f*x*x*x);
          v = 0.5f*x*(1.0f + tanhf(inner));
        }
        size_t off = (size_t)row*N + col;
        if (flags & 4){
          ushort_t h, l; split2(v, h, l);
          out_hi[off] = h; out_lo[off] = l;
        } else if (flags & 1){
          outF[off] += v;
        } else {
          outF[off] = v;
        }
      }
    }
  }
}

// ---------------- LSH bucketing from split qv planes
__global__ __launch_bounds__(256) void k_buckets(const ushort_t* __restrict__ qv_hi,
                                                 const ushort_t* __restrict__ qv_lo,
                                                 const float* __restrict__ rot,
                                                 int* __restrict__ buckets){
  __shared__ float rotS[DH_][32];
  __shared__ float qs[64][68];
  int t0 = blockIdx.x * 64;
  int h  = blockIdx.y;
  int bh = blockIdx.z;
  int b = bh >> 3, head = bh & 7;
  int tid = threadIdx.x;
  for (int idx = tid; idx < DH_*32; idx += 256){
    int d = idx >> 5, j = idx & 31;
    rotS[d][j] = rot[(size_t)d*(NHASH_*32) + h*32 + j];
  }
  for (int idx = tid; idx < 64*DH_; idx += 256){
    int tt = idx >> 6, d = idx & 63;
    size_t off = ((size_t)(b*T_ + t0 + tt))*QV_N + head*DH_ + d;
    qs[tt][d] = bf2f(qv_hi[off]) + bf2f(qv_lo[off]);
  }
  __syncthreads();
  int tt = tid >> 2, lane = tid & 3;
  int j0 = lane * 8;
  float r8[8];
  #pragma unroll
  for (int k=0;k<8;k++) r8[k] = 0.f;
  for (int d=0; d<DH_; d++){
    float q = qs[tt][d];
    #pragma unroll
    for (int k=0;k<8;k++) r8[k] += q * rotS[d][j0+k];
  }
  float best = r8[0]; int bidx = j0;
  #pragma unroll
  for (int k=1;k<8;k++){ if (r8[k] > best){ best = r8[k]; bidx = j0+k; } }
  #pragma unroll
  for (int k=0;k<8;k++){ float v = -r8[k]; if (v > best){ best = v; bidx = 32+j0+k; } }
  #pragma unroll
  for (int x=1; x<=2; x<<=1){
    float ov = __shfl_xor(best, x);
    int   oi = __shfl_xor(bidx, x);
    if (ov > best || (ov == best && oi < bidx)){ best = ov; bidx = oi; }
  }
  if (lane == 0)
    buckets[((size_t)bh*NHASH_ + h)*T_ + t0 + tt] = bidx;
}

// ---------------- stable counting sort per (bh, hash)
__global__ __launch_bounds__(256) void k_sort(const int* __restrict__ buckets,
                                              int* __restrict__ st){
  int blk = blockIdx.x;
  int bh = blk >> 3, h = blk & 7;
  const int* bptr = buckets + ((size_t)bh*NHASH_ + h)*T_;
  __shared__ unsigned char bb[T_];
  __shared__ int cnt[4][NB_];
  __shared__ int offs[NB_];
  int tid = threadIdx.x;
  for (int i = tid; i < T_; i += 256) bb[i] = (unsigned char)bptr[i];
  __syncthreads();
  int q = tid >> 6, j = tid & 63;
  int c0 = 0;
  for (int t = q*1024; t < q*1024 + 1024; t++) c0 += (bb[t]==j) ? 1 : 0;
  cnt[q][j] = c0;
  __syncthreads();
  if (tid == 0){
    int run = 0;
    for (int jj=0; jj<NB_; jj++){
      offs[jj] = run;
      run += cnt[0][jj] + cnt[1][jj] + cnt[2][jj] + cnt[3][jj];
    }
  }
  __syncthreads();
  int off = offs[j];
  for (int qq=0; qq<q; qq++) off += cnt[qq][j];
  size_t base = (size_t)bh*SORTN_ + (size_t)h*T_;
  for (int t = q*1024; t < q*1024 + 1024; t++){
    if (bb[t]==j){ st[base+off] = t; off++; }
  }
}

// ---------------- flash-MFMA LSH attention; inputs pre-split qv planes
__global__ __launch_bounds__(256) void k_attn(const ushort_t* __restrict__ qv_hi,
                                              const ushort_t* __restrict__ qv_lo,
                                              const int* __restrict__ st,
                                              float* __restrict__ lse_un,
                                              float* __restrict__ o_un, int bh0){
  __shared__ ushort_t tileh[128*72];
  __shared__ ushort_t tilel[128*72];
  __shared__ float nrm[128];
  __shared__ int spos[128];
  int blk = blockIdx.x;
  int hh = blk >> 9;
  int bh = bh0 + hh;
  int c = blk & (NCH_-1);
  int h = c >> 6;
  int b = bh >> 3, head = bh & 7;
  int cprev = (c + NCH_ - 1) & (NCH_-1);
  int tid = threadIdx.x;
  const int* stb = st + (size_t)bh * SORTN_;
  if (tid < 128){
    int gc = (tid < 64) ? c : cprev;
    spos[tid] = stb[gc*64 + (tid & 63)];
    nrm[tid] = 0.f;
  }
  __syncthreads();
  // stage QK rows (split planes) + row norms
  for (int idx = tid; idx < 128*8; idx += 256){
    int j = idx >> 3, c8 = (idx & 7) * 8;
    size_t off = ((size_t)(b*T_ + spos[j]))*QV_N + head*DH_ + c8;
    uint4 hv = *(const uint4*)(qv_hi + off);
    uint4 lv = *(const uint4*)(qv_lo + off);
    *(uint4*)&tileh[j*72 + c8] = hv;
    *(uint4*)&tilel[j*72 + c8] = lv;
    const uint32 hw[4] = {hv.x,hv.y,hv.z,hv.w};
    const uint32 lw[4] = {lv.x,lv.y,lv.z,lv.w};
    float ss = 0.f;
    #pragma unroll
    for (int e=0;e<4;e++){
      float a0 = bf2f((ushort_t)(hw[e] & 0xffffu)) + bf2f((ushort_t)(lw[e] & 0xffffu));
      float a1 = bf2f((ushort_t)(hw[e] >> 16))     + bf2f((ushort_t)(lw[e] >> 16));
      ss += a0*a0 + a1*a1;
    }
    atomicAdd(&nrm[j], ss);
  }
  __syncthreads();
  if (tid < 128) nrm[tid] = 1.0f / sqrtf(fmaxf(nrm[tid], 1e-30f));
  int w = tid >> 6, lane = tid & 63;
  int lr = lane & 15, quad = lane >> 4;
  __syncthreads();
  // S = Qraw x Kraw^T
  v4f sacc[8];
  #pragma unroll
  for (int nt=0;nt<8;nt++) sacc[nt] = (v4f){0.f,0.f,0.f,0.f};
  #pragma unroll
  for (int ks=0; ks<2; ks++){
    int ao = (w*16 + lr)*72 + ks*32 + quad*8;
    v8s fah = *(const v8s*)&tileh[ao];
    v8s fal = *(const v8s*)&tilel[ao];
    #pragma unroll
    for (int nt=0; nt<8; nt++){
      int bo = (nt*16 + lr)*72 + ks*32 + quad*8;
      v8s fbh = *(const v8s*)&tileh[bo];
      v8s fbl = *(const v8s*)&tilel[bo];
      sacc[nt] = __builtin_amdgcn_mfma_f32_16x16x32_bf16(fah, fbh, sacc[nt],0,0,0);
      sacc[nt] = __builtin_amdgcn_mfma_f32_16x16x32_bf16(fah, fbl, sacc[nt],0,0,0);
      sacc[nt] = __builtin_amdgcn_mfma_f32_16x16x32_bf16(fal, fbh, sacc[nt],0,0,0);
    }
  }
  int q0 = w*16 + quad*4;
  int pq[4];
  #pragma unroll
  for (int r=0;r<4;r++) pq[r] = spos[q0 + r];
  float mrow[4] = {-3e38f,-3e38f,-3e38f,-3e38f};
  #pragma unroll
  for (int nt=0;nt<8;nt++){
    int j = nt*16 + lr;
    float sc = nrm[j] * 0.125f;
    int pk = spos[j];
    #pragma unroll
    for (int r=0;r<4;r++){
      float s = sacc[nt][r] * sc;
      if (pk == pq[r]) s = -5.0e4f;
      sacc[nt][r] = s;
      mrow[r] = fmaxf(mrow[r], s);
    }
  }
  #pragma unroll
  for (int r=0;r<4;r++){
    #pragma unroll
    for (int x=1;x<=8;x<<=1) mrow[r] = fmaxf(mrow[r], __shfl_xor(mrow[r], x));
  }
  float srow[4] = {0.f,0.f,0.f,0.f};
  #pragma unroll
  for (int nt=0;nt<8;nt++){
    #pragma unroll
    for (int r=0;r<4;r++){
      float e = expf(sacc[nt][r] - mrow[r]);
      sacc[nt][r] = e;
      srow[r] += e;
    }
  }
  #pragma unroll
  for (int r=0;r<4;r++){
    #pragma unroll
    for (int x=1;x<=8;x<<=1) srow[r] += __shfl_xor(srow[r], x);
  }
  size_t obase = ((size_t)(hh*NHASH_ + h))*T_;
  if (lr == 0){
    #pragma unroll
    for (int r=0;r<4;r++)
      lse_un[obase + pq[r]] = mrow[r] + logf(srow[r]);
  }
  float rs[4];
  #pragma unroll
  for (int r=0;r<4;r++) rs[r] = 1.0f / srow[r];
  __syncthreads();
  // P round-trip
  #pragma unroll
  for (int nt=0;nt<8;nt++){
    #pragma unroll
    for (int r=0;r<4;r++){
      float p = sacc[nt][r] * rs[r];
      ushort_t ph, pl; split2(p, ph, pl);
      int o = (q0 + r)*136 + nt*16 + lr;
      tileh[o] = ph; tilel[o] = pl;
    }
  }
  __syncthreads();
  v8s pah[4], pal[4];
  #pragma unroll
  for (int ks=0; ks<4; ks++){
    int ao = (w*16 + lr)*136 + ks*32 + quad*8;
    pah[ks] = *(const v8s*)&tileh[ao];
    pal[ks] = *(const v8s*)&tilel[ao];
  }
  __syncthreads();
  // stage V transposed (from split planes, cols 512..1023 of qv)
  for (int idx = tid; idx < 128*8; idx += 256){
    int j = idx >> 3, c8 = (idx & 7) * 8;
    size_t off = ((size_t)(b*T_ + spos[j]))*QV_N + 512 + head*DH_ + c8;
    uint4 hv = *(const uint4*)(qv_hi + off);
    uint4 lv = *(const uint4*)(qv_lo + off);
    const uint32 hw[4] = {hv.x,hv.y,hv.z,hv.w};
    const uint32 lw[4] = {lv.x,lv.y,lv.z,lv.w};
    #pragma unroll
    for (int e=0;e<4;e++){
      tileh[(c8+2*e+0)*136 + j] = (ushort_t)(hw[e] & 0xffffu);
      tileh[(c8+2*e+1)*136 + j] = (ushort_t)(hw[e] >> 16);
      tilel[(c8+2*e+0)*136 + j] = (ushort_t)(lw[e] & 0xffffu);
      tilel[(c8+2*e+1)*136 + j] = (ushort_t)(lw[e] >> 16);
    }
  }
  __syncthreads();
  // O = P x V
  v4f oacc[4];
  #pragma unroll
  for (int nt=0;nt<4;nt++) oacc[nt] = (v4f){0.f,0.f,0.f,0.f};
  #pragma unroll
  for (int ks=0; ks<4; ks++){
    #pragma unroll
    for (int nt=0; nt<4; nt++){
      int bo = (nt*16 + lr)*136 + ks*32 + quad*8;
      v8s vbh = *(const v8s*)&tileh[bo];
      v8s vbl = *(const v8s*)&tilel[bo];
      oacc[nt] = __builtin_amdgcn_mfma_f32_16x16x32_bf16(pah[ks], vbh, oacc[nt],0,0,0);
      oacc[nt] = __builtin_amdgcn_mfma_f32_16x16x32_bf16(pah[ks], vbl, oacc[nt],0,0,0);
      oacc[nt] = __builtin_amdgcn_mfma_f32_16x16x32_bf16(pal[ks], vbh, oacc[nt],0,0,0);
    }
  }
  #pragma unroll
  for (int r=0;r<4;r++){
    size_t rowoff = (obase + pq[r])*64;
    #pragma unroll
    for (int nt=0;nt<4;nt++){
      o_un[rowoff + nt*16 + lr] = oacc[nt][r];
    }
  }
}

// ---------------- combine hash rounds (coalesced)
__global__ __launch_bounds__(512) void k_combine(const float* __restrict__ lse_un,
                                                 const float* __restrict__ o_un,
                                                 ushort_t* __restrict__ ctx_hi,
                                                 ushort_t* __restrict__ ctx_lo,
                                                 int row0){
  int row = row0 + blockIdx.x;
  int t = row & (T_-1);
  int head = threadIdx.x >> 6, d = threadIdx.x & 63;
  float l[NHASH_];
  float m = -3.0e38f;
  #pragma unroll
  for (int h=0; h<NHASH_; h++){
    l[h] = lse_un[((size_t)(head*NHASH_ + h))*T_ + t];
    m = fmaxf(m, l[h]);
  }
  float sum = 0.f;
  #pragma unroll
  for (int h=0; h<NHASH_; h++){ l[h] = expf(l[h]-m); sum += l[h]; }
  float rsv = 1.0f/sum;
  float acc = 0.f;
  #pragma unroll
  for (int h=0; h<NHASH_; h++){
    acc += l[h] * o_un[(((size_t)(head*NHASH_ + h))*T_ + t)*64 + d];
  }
  float o = acc * rsv;
  ushort_t hi, lo; split2(o, hi, lo);
  size_t off = (size_t)row*DIM_ + head*DH_ + d;
  ctx_hi[off] = hi; ctx_lo[off] = lo;
}

// ---------------- final head
__global__ __launch_bounds__(64) void k_final(const float* __restrict__ xn,
                                              const float* __restrict__ Wout,
                                              const float* __restrict__ bout,
                                              float* __restrict__ out){
  int row = blockIdx.x;
  int lane = threadIdx.x;
  const float* xr = xn + (size_t)row*DIM_;
  float p[TAGS_];
  #pragma unroll
  for (int n=0;n<TAGS_;n++) p[n] = 0.f;
  for (int d = lane; d < DIM_; d += 64){
    float x = xr[d];
    const float* wr = Wout + (size_t)d*TAGS_;
    #pragma unroll
    for (int n=0;n<TAGS_;n++) p[n] += x * wr[n];
  }
  #pragma unroll
  for (int n=0;n<TAGS_;n++){
    #pragma unroll
    for (int o=32;o>0;o>>=1) p[n] += __shfl_xor(p[n], o);
  }
  if (lane == 0){
    for (int n=0;n<TAGS_;n++) out[(size_t)row*TAGS_ + n] = p[n] + bout[n];
  }
}

extern "C" void kernel_launch(void* const* d_in, const int* in_sizes, int n_in,
                              void* d_out, int out_size, void* d_ws, size_t ws_size,
                              hipStream_t stream){
  const int* X         = (const int*)d_in[0];
  const float* tok     = (const float*)d_in[1];
  const float* ax1     = (const float*)d_in[2];
  const float* ax2     = (const float*)d_in[3];
  const float* Wqk     = (const float*)d_in[4];
  const float* Wv      = (const float*)d_in[5];
  const float* Wo      = (const float*)d_in[6];
  const float* ln1g    = (const float*)d_in[7];
  const float* ln1b    = (const float*)d_in[8];
  const float* W1      = (const float*)d_in[9];
  const float* b1      = (const float*)d_in[10];
  const float* W2      = (const float*)d_in[11];
  const float* b2      = (const float*)d_in[12];
  const float* ln2g    = (const float*)d_in[13];
  const float* ln2b    = (const float*)d_in[14];
  const float* lnfg    = (const float*)d_in[15];
  const float* lnfb    = (const float*)d_in[16];
  const float* WoutP   = (const float*)d_in[17];
  const float* boutP   = (const float*)d_in[18];
  const float* rot     = (const float*)d_in[19];
  float* out = (float*)d_out;

  size_t NX = (size_t)ROWS_*DIM_;            // 4,194,304
  size_t NS = (size_t)BH_*SORTN_;            // 524,288
  const size_t S3  = (size_t)DIM_*DIM_;      // 262,144
  const size_t SW1 = (size_t)DIM_*FF_;       // 1,048,576
  // per-layer weight arena (ushorts): qvw pair (2*2*S3) + wo pair + w1 pair + w2 pair
  const size_t WL  = 4*S3 + 2*S3 + 2*SW1 + 2*SW1;   // 5,767,168

  float* x1 = (float*)d_ws;
  float* x2 = x1 + NX;
  float* lse_un = x2 + NX;                   // NS floats
  int* buckets = (int*)(lse_un + NS);
  int* st  = buckets + NS;
  ushort_t* act_hi = (ushort_t*)(st + NS);   // [ROWS][512] split ctx/ln planes
  ushort_t* act_lo = act_hi + NX;
  ushort_t* qv_hi = act_lo + NX;             // [ROWS][1024] fused qk|v split planes
  ushort_t* qv_lo = qv_hi + (size_t)ROWS_*QV_N;
  ushort_t* warena = qv_lo + (size_t)ROWS_*QV_N;
  float* o_un = (float*)(warena + 2*WL);     // 64 MiB
  ushort_t* ffh_hi = (ushort_t*)o_un;        // FF hidden planes alias o_un
  ushort_t* ffh_lo = ffh_hi + (size_t)ROWS_*FF_;
  float* fbuf = (float*)o_un;                // final-LN fp32 (after FF dead)

  for (int l=0; l<2; l++){
    ushort_t* wl = warena + (size_t)l*WL;
    ushort_t* qvw_h = wl;                    // [1024][512]: rows 0-511 Wqk^T, 512-1023 Wv^T
    ushort_t* qvw_l = qvw_h + 2*S3;
    ushort_t* wo_h  = qvw_l + 2*S3;  ushort_t* wo_l = wo_h + S3;
    ushort_t* w1_h  = wo_l + S3;     ushort_t* w1_l = w1_h + SW1;
    ushort_t* w2_h  = w1_l + SW1;    ushort_t* w2_l = w2_h + SW1;
    k_splitw<<<dim3(DIM_/32, DIM_/32), 256, 0, stream>>>(Wqk + (size_t)l*S3, qvw_h, qvw_l, DIM_, DIM_);
    k_splitw<<<dim3(DIM_/32, DIM_/32), 256, 0, stream>>>(Wv  + (size_t)l*S3, qvw_h + S3, qvw_l + S3, DIM_, DIM_);
    k_splitw<<<dim3(DIM_/32, DIM_/32), 256, 0, stream>>>(Wo  + (size_t)l*S3, wo_h, wo_l, DIM_, DIM_);
    k_splitw<<<dim3(FF_/32,  DIM_/32), 256, 0, stream>>>(W1  + (size_t)l*SW1, w1_h, w1_l, DIM_, FF_);
    k_splitw<<<dim3(DIM_/32, FF_/32),  256, 0, stream>>>(W2  + (size_t)l*SW1, w2_h, w2_l, FF_, DIM_);
  }

  k_embed<<<ROWS_, 256, 0, stream>>>(X, tok, ax1, ax2, x1, x2);
  for (int l=0; l<2; l++){
    ushort_t* wl = warena + (size_t)l*WL;
    ushort_t* qvw_h = wl;
    ushort_t* qvw_l = qvw_h + 2*S3;
    ushort_t* wo_h  = qvw_l + 2*S3;  ushort_t* wo_l = wo_h + S3;
    ushort_t* w1_h  = wo_l + S3;     ushort_t* w1_l = w1_h + SW1;
    ushort_t* w2_h  = w1_l + SW1;    ushort_t* w2_l = w2_h + SW1;
    const float* rot_l = rot + (size_t)l*DH_*NHASH_*32;

    k_ln<<<ROWS_, 256, 0, stream>>>(x2, nullptr, ln1g + l*DIM_, ln1b + l*DIM_, nullptr, act_hi, act_lo);
    k_gemm_mfma<<<dim3(QV_N/128, ROWS_/128), 256, 0, stream>>>(
        act_hi, act_lo, qvw_h, qvw_l, nullptr, nullptr, qv_hi, qv_lo, ROWS_, QV_N, DIM_, 4);
    k_buckets<<<dim3(T_/64, NHASH_, BH_), 256, 0, stream>>>(qv_hi, qv_lo, rot_l, buckets);
    k_sort<<<BH_*NHASH_, 256, 0, stream>>>(buckets, st);
    k_attn<<<8*NCH_, 256, 0, stream>>>(qv_hi, qv_lo, st, lse_un, o_un, 0);
    k_combine<<<T_, 512, 0, stream>>>(lse_un, o_un, act_hi, act_lo, 0);
    k_attn<<<8*NCH_, 256, 0, stream>>>(qv_hi, qv_lo, st, lse_un, o_un, 8);
    k_combine<<<T_, 512, 0, stream>>>(lse_un, o_un, act_hi, act_lo, T_);
    k_gemm_mfma<<<dim3(DIM_/128, ROWS_/128), 256, 0, stream>>>(
        act_hi, act_lo, wo_h, wo_l, nullptr, x1, nullptr, nullptr, ROWS_, DIM_, DIM_, 1);
    k_ln<<<ROWS_, 256, 0, stream>>>(x1, nullptr, ln2g + l*DIM_, ln2b + l*DIM_, nullptr, act_hi, act_lo);
    k_gemm_mfma<<<dim3(FF_/128, ROWS_/128), 256, 0, stream>>>(
        act_hi, act_lo, w1_h, w1_l, b1 + l*FF_, nullptr, ffh_hi, ffh_lo, ROWS_, FF_, DIM_, 2|4);
    k_gemm_mfma<<<dim3(DIM_/128, ROWS_/128), 256, 0, stream>>>(
        ffh_hi, ffh_lo, w2_h, w2_l, b2 + l*DIM_, x2, nullptr, nullptr, ROWS_, DIM_, FF_, 1);
  }
  k_ln<<<ROWS_, 256, 0, stream>>>(x1, x2, lnfg, lnfb, fbuf, nullptr, nullptr);
  k_final<<<ROWS_, 64, 0, stream>>>(fbuf, WoutP, boutP, out);
}